// Round 11
// baseline (4760.959 us; speedup 1.0000x reference)
//
#include <hip/hip_runtime.h>
#include <hip/hip_bf16.h>
#include <float.h>
#include <stdint.h>

// Problem constants (fixed by setup_inputs): B=4, N=M=4096, D=3.
#define BATCH 4
#define NPTS  4096
#define TOT   (BATCH * NPTS)   // 16384

// ---------------------------------------------------------------------------
// Kernel 1: pack points into float4 {x, y, z, |p|^2}.
// rr is x*x + y*y + z*z left-to-right, matching jnp.sum(x*x, -1).
// ---------------------------------------------------------------------------
__global__ __launch_bounds__(256) void pack_kernel(
    const float* __restrict__ gts, const float* __restrict__ preds,
    float4* __restrict__ pkG, float4* __restrict__ pkP)
{
    int i = blockIdx.x * blockDim.x + threadIdx.x;   // 0 .. 2*TOT-1
    if (i >= 2 * TOT) return;
    const float* src = (i < TOT) ? gts : preds;
    float4* dst      = (i < TOT) ? pkG : pkP;
    int k            = (i < TOT) ? i : i - TOT;
    float x = src[3 * k + 0];
    float y = src[3 * k + 1];
    float z = src[3 * k + 2];
    float rr = __fadd_rn(__fadd_rn(__fmul_rn(x, x), __fmul_rn(y, y)), __fmul_rn(z, z));
    dst[k] = make_float4(x, y, z, rr);
}

// ---------------------------------------------------------------------------
// Kernel 2: per-(side,batch) bitonic sort by x (8 blocks, 1024 threads, LDS).
// 64-bit keys {monotone_bits(x) << 32 | idx} -> total order, deterministic.
// Outputs: sx (sorted float4), si (original batch-local idx), xs (sorted x).
// Layout: [side(2)][batch(4)][4096], side 0 = gts, side 1 = preds.
// ---------------------------------------------------------------------------
__global__ __launch_bounds__(1024) void sort_kernel(
    const float4* __restrict__ pkG, const float4* __restrict__ pkP,
    float4* __restrict__ sx, int* __restrict__ si, float* __restrict__ xs)
{
    __shared__ unsigned long long keys[NPTS];   // 32 KB
    int side = blockIdx.x >> 2;
    int b = blockIdx.x & 3;
    const float4* src = (side ? pkP : pkG) + (b << 12);
    for (int t = threadIdx.x; t < NPTS; t += 1024) {
        unsigned u = __float_as_uint(src[t].x);
        u = (u & 0x80000000u) ? ~u : (u | 0x80000000u);   // monotone map
        keys[t] = ((unsigned long long)u << 32) | (unsigned)t;
    }
    __syncthreads();
    for (int k = 2; k <= NPTS; k <<= 1) {
        for (int j = k >> 1; j > 0; j >>= 1) {
            for (int t = threadIdx.x; t < NPTS; t += 1024) {
                int ixj = t ^ j;
                if (ixj > t) {
                    unsigned long long a = keys[t], c = keys[ixj];
                    bool up = (t & k) == 0;
                    if (up ? (a > c) : (a < c)) { keys[t] = c; keys[ixj] = a; }
                }
            }
            __syncthreads();
        }
    }
    int base = (int)blockIdx.x << 12;
    for (int t = threadIdx.x; t < NPTS; t += 1024) {
        int orig = (int)(unsigned)(keys[t] & 0xFFFFFFFFu);
        float4 v = src[orig];
        sx[base + t] = v;
        si[base + t] = orig;
        xs[base + t] = v.x;
    }
}

// ---------------------------------------------------------------------------
// Rounds 0-3: sorted-window argmin search. 2 lanes per own point (even lane
// scans left, odd lane scans right from the binary-search insertion point).
// d computed with the EXACT verified formula; lex (d, j) updates == numpy
// first-argmin tie-break (scan-order independent). A side stops when
// fl(dx)^2 > min(pair best) + MARGIN; dx^2 lower-bounds d_true and
// |fl(d)-d_true| <= ~4e-5 << MARGIN = 1e-3, and best only decreases, so no
// candidate that could achieve or tie the minimal computed d is pruned.
// Exclusions (round R): j == e_t  OR  rev_t[j] == ownIn for t < R, inline.
// All-excluded row -> bestj = 0 (= numpy argmin of an all-max row).
// ---------------------------------------------------------------------------
template<int R>
__global__ __launch_bounds__(256) void search_kernel(
    const float4* __restrict__ sx, const int* __restrict__ si,
    const float* __restrict__ xs,
    const int* __restrict__ is0, const int* __restrict__ is1, const int* __restrict__ is2,
    const int* __restrict__ if0, const int* __restrict__ if1, const int* __restrict__ if2,
    float* __restrict__ dS, int* __restrict__ iS,
    float* __restrict__ dF, int* __restrict__ iF,
    int do_rows)
{
    int tid = blockIdx.x * 256 + threadIdx.x;
    int task = tid >> 1;
    int side = tid & 1;                  // 0: left scan, 1: right scan
    int half = do_rows ? TOT : 0;
    bool isRow = task < half;            // s2f: own = gts, other = preds
    int t = isRow ? task : task - half;  // (b, sorted own position p)
    int b = t >> 12, p = t & (NPTS - 1);
    int obase = b << 12;

    int ownSide = isRow ? 0 : 1;
    int obOwn = ((ownSide << 2) | b) << 12;
    int obOth = (((1 - ownSide) << 2) | b) << 12;
    const float4* sOwn = sx + obOwn;
    const int*    iOwn = si + obOwn;
    const float4* sOth = sx + obOth;
    const int*    iOth = si + obOth;
    const float*  xOth = xs + obOth;

    float4 ow = sOwn[p];
    int ownIn = iOwn[p];

    int e0 = -1, e1 = -1, e2 = -1;
    if (R > 0) e0 = (isRow ? is0 : if0)[obase + ownIn];
    if (R > 1) e1 = (isRow ? is1 : if1)[obase + ownIn];
    if (R > 2) e2 = (isRow ? is2 : if2)[obase + ownIn];
    const int* r0 = (R > 0) ? (isRow ? if0 : is0) + obase : nullptr;
    const int* r1 = (R > 1) ? (isRow ? if1 : is1) + obase : nullptr;
    const int* r2 = (R > 2) ? (isRow ? if2 : is2) + obase : nullptr;

    // lower bound of own.x in sorted-other x
    float bx = ow.x;
    int lo = 0, hi = NPTS;
    while (lo < hi) {
        int mid = (lo + hi) >> 1;
        if (xOth[mid] < bx) lo = mid + 1; else hi = mid;
    }
    int ptr  = side ? lo : lo - 1;
    int step = side ? 1 : -1;

    float best = FLT_MAX; int bestj = 0;
    bool done = false;
    const float MARGIN = 1e-3f;
    for (;;) {
        if (!__ballot(!done)) break;
        float pb = __shfl_xor(best, 1);                // pair-shared bound
        float bs = fminf(best, pb) + MARGIN;
        if (!done) {
            if ((unsigned)ptr >= (unsigned)NPTS) {
                done = true;
            } else {
                float qx = xOth[ptr];
                float dx = side ? (qx - bx) : (bx - qx);   // >= 0
                if (__fmul_rn(dx, dx) > bs) {
                    done = true;                            // monotone -> side done
                } else {
                    float4 q = sOth[ptr];
                    int j = iOth[ptr];
                    float zz = __fadd_rn(__fadd_rn(__fmul_rn(ow.x, q.x),
                                                   __fmul_rn(ow.y, q.y)),
                                         __fmul_rn(ow.z, q.z));
                    float d = __fmaf_rn(-2.0f, zz, __fadd_rn(ow.w, q.w));
                    bool ex = false;
                    if (R > 0) ex = (j == e0) || (r0[j] == ownIn);
                    if (R > 1) ex = ex || (j == e1) || (r1[j] == ownIn);
                    if (R > 2) ex = ex || (j == e2) || (r2[j] == ownIn);
                    if (!ex && (d < best || (d == best && j < bestj))) {
                        best = d; bestj = j;
                    }
                    ptr += step;
                }
            }
        }
    }
    // combine the pair (lex on (d, j))
    float ob = __shfl_xor(best, 1);
    int   oj = __shfl_xor(bestj, 1);
    if (ob < best || (ob == best && oj < bestj)) { best = ob; bestj = oj; }
    if (side == 0) {
        if (isRow) { iS[obase + ownIn] = bestj; if (R == 0) dS[obase + ownIn] = best; }
        else       { iF[obase + ownIn] = bestj; if (R == 0) dF[obase + ownIn] = best; }
    }
}

// ---------------------------------------------------------------------------
// Fallback full-rescan kernel (verified in R4) — used only if ws too small.
// ---------------------------------------------------------------------------
template<int R>
__global__ __launch_bounds__(256) void round_full_kernel(
    const float4* __restrict__ pkG, const float4* __restrict__ pkP,
    const int* __restrict__ is0, const int* __restrict__ is1, const int* __restrict__ is2,
    const int* __restrict__ if0, const int* __restrict__ if1, const int* __restrict__ if2,
    float* __restrict__ dS, int* __restrict__ iS,
    float* __restrict__ dF, int* __restrict__ iF,
    int do_rows)
{
    int half    = do_rows ? (gridDim.x >> 1) : gridDim.x;
    bool isRow  = do_rows && ((int)blockIdx.x < half);
    int dirBlk  = isRow ? blockIdx.x : (blockIdx.x - (do_rows ? half : 0));

    const float4* own = isRow ? pkG : pkP;
    const float4* oth = isRow ? pkP : pkG;
    const int* exOwn0 = isRow ? is0 : if0;
    const int* exOwn1 = isRow ? is1 : if1;
    const int* exOwn2 = isRow ? is2 : if2;
    const int* exOth0 = isRow ? if0 : is0;
    const int* exOth1 = isRow ? if1 : is1;
    const int* exOth2 = isRow ? if2 : is2;
    float* dOut = isRow ? dS : dF;
    int*   iOut = isRow ? iS : iF;

    int lane = threadIdx.x & 63;
    int wave = threadIdx.x >> 6;
    int ownBase = dirBlk * 16 + wave * 4;
    int b = ownBase >> 12;
    int obase = b << 12;

    float ox[4], oy[4], oz[4], orr[4];
    int ownIn[4];
    int oe0[4], oe1[4], oe2[4];
    #pragma unroll
    for (int r = 0; r < 4; ++r) {
        float4 p = own[ownBase + r];
        ox[r] = p.x; oy[r] = p.y; oz[r] = p.z; orr[r] = p.w;
        ownIn[r] = (ownBase & (NPTS - 1)) + r;
        oe0[r] = 0; oe1[r] = 0; oe2[r] = 0;
        if (R > 0) oe0[r] = exOwn0[ownBase + r];
        if (R > 1) oe1[r] = exOwn1[ownBase + r];
        if (R > 2) oe2[r] = exOwn2[ownBase + r];
    }

    float best[4]; int bidx[4];
    #pragma unroll
    for (int r = 0; r < 4; ++r) { best[r] = FLT_MAX; bidx[r] = 0; }

    for (int j = lane; j < NPTS; j += 64) {
        float4 q = oth[obase + j];
        int eo0 = 0, eo1 = 0, eo2 = 0;
        if (R > 0) eo0 = exOth0[obase + j];
        if (R > 1) eo1 = exOth1[obase + j];
        if (R > 2) eo2 = exOth2[obase + j];
        #pragma unroll
        for (int r = 0; r < 4; ++r) {
            float zz = __fadd_rn(__fadd_rn(__fmul_rn(ox[r], q.x),
                                           __fmul_rn(oy[r], q.y)),
                                 __fmul_rn(oz[r], q.z));
            float d = __fmaf_rn(-2.0f, zz, __fadd_rn(orr[r], q.w));
            bool ex = false;
            if (R > 0) ex = ex || (j == oe0[r]) || (eo0 == ownIn[r]);
            if (R > 1) ex = ex || (j == oe1[r]) || (eo1 == ownIn[r]);
            if (R > 2) ex = ex || (j == oe2[r]) || (eo2 == ownIn[r]);
            if (ex) d = FLT_MAX;
            if (d < best[r]) { best[r] = d; bidx[r] = j; }
        }
    }

    #pragma unroll
    for (int r = 0; r < 4; ++r) {
        float v = best[r]; int ix = bidx[r];
        #pragma unroll
        for (int off = 32; off > 0; off >>= 1) {
            float v2 = __shfl_xor(v, off);
            int   i2 = __shfl_xor(ix, off);
            if (v2 < v || (v2 == v && i2 < ix)) { v = v2; ix = i2; }
        }
        if (lane == 0) {
            iOut[ownBase + r] = ix;
            if (dOut) dOut[ownBase + r] = v;
        }
    }
}

// ---------------------------------------------------------------------------
// Per-(batch, segment) partial sums (unchanged, verified).
// ---------------------------------------------------------------------------
__global__ __launch_bounds__(256) void normal_kernel(
    const float* __restrict__ preds, const float* __restrict__ normals,
    const float* __restrict__ dS, const float* __restrict__ dF,
    const int* __restrict__ if0, const int* __restrict__ if1,
    const int* __restrict__ if2, const int* __restrict__ if3,
    float4* __restrict__ partials)
{
    int b   = blockIdx.x >> 2;
    int seg = blockIdx.x & 3;
    int t   = threadIdx.x;

    const float* pp = preds + (size_t)b * NPTS * 3;
    float champ = 0.f, s1 = 0.f, s2 = 0.f, s3 = 0.f;

    for (int it = 0; it < 4; ++it) {
        int m  = seg * 1024 + it * 256 + t;
        int gi = b * NPTS + m;
        champ += dF[gi] + dS[gi];

        int i0 = if0[gi];
        float p0x = pp[3 * i0 + 0], p0y = pp[3 * i0 + 1], p0z = pp[3 * i0 + 2];
        float nx = normals[3 * gi + 0], ny = normals[3 * gi + 1], nz = normals[3 * gi + 2];

        int iA = if1[gi];
        s1 += (p0x - pp[3 * iA + 0]) * nx + (p0y - pp[3 * iA + 1]) * ny + (p0z - pp[3 * iA + 2]) * nz;
        int iB = if2[gi];
        s2 += (p0x - pp[3 * iB + 0]) * nx + (p0y - pp[3 * iB + 1]) * ny + (p0z - pp[3 * iB + 2]) * nz;
        int iC = if3[gi];
        s3 += (p0x - pp[3 * iC + 0]) * nx + (p0y - pp[3 * iC + 1]) * ny + (p0z - pp[3 * iC + 2]) * nz;
    }

    #pragma unroll
    for (int off = 32; off > 0; off >>= 1) {
        champ += __shfl_xor(champ, off);
        s1    += __shfl_xor(s1, off);
        s2    += __shfl_xor(s2, off);
        s3    += __shfl_xor(s3, off);
    }
    __shared__ float4 red[4];
    int wave = t >> 6, lane = t & 63;
    if (lane == 0) red[wave] = make_float4(champ, s1, s2, s3);
    __syncthreads();
    if (t == 0) {
        float4 a = red[0];
        for (int w = 1; w < 4; ++w) {
            a.x += red[w].x; a.y += red[w].y; a.z += red[w].z; a.w += red[w].w;
        }
        partials[blockIdx.x] = a;
    }
}

__global__ void final_kernel(const float4* __restrict__ partials, float* __restrict__ out)
{
    if (blockIdx.x == 0 && threadIdx.x == 0) {
        float champ = 0.f;
        float s[BATCH][3];
        for (int b = 0; b < BATCH; ++b) for (int k = 0; k < 3; ++k) s[b][k] = 0.f;
        for (int blk = 0; blk < 16; ++blk) {
            float4 p = partials[blk];
            int b = blk >> 2;
            champ   += p.x;
            s[b][0] += p.y;
            s[b][1] += p.z;
            s[b][2] += p.w;
        }
        float nl = 0.f;
        for (int k = 0; k < 3; ++k)
            for (int b = 0; b < BATCH; ++b)
                nl += fabsf(s[b][k]);
        out[0] = 1.0f + champ + 10.0f * nl;
    }
}

// ---------------------------------------------------------------------------
// Launch. Workspace (~1.9 MB):
//   pkG | pkP (256 KB ea) | sx (512 KB) | si (128 KB) | xs (128 KB) |
//   iS0..iS2, iF0..iF3 (7 x 64 KB) | dS0 | dF0 | partials
// Fallback: verified full-rescan chain if ws too small.
// ---------------------------------------------------------------------------
extern "C" void kernel_launch(void* const* d_in, const int* in_sizes, int n_in,
                              void* d_out, int out_size, void* d_ws, size_t ws_size,
                              hipStream_t stream) {
    const float* gts     = (const float*)d_in[0];
    const float* preds   = (const float*)d_in[1];
    const float* normals = (const float*)d_in[2];
    float* out = (float*)d_out;

    char* ws = (char*)d_ws;
    float4* pkG = (float4*)ws;
    float4* pkP = (float4*)(ws + 262144);
    float4* sx  = (float4*)(ws + 524288);
    int*    si  = (int*)(ws + 1048576);
    float*  xsb = (float*)(ws + 1179648);
    int* iS0 = (int*)(ws + 1310720);
    int* iS1 = iS0 + TOT;
    int* iS2 = iS1 + TOT;
    int* iF0 = iS2 + TOT;
    int* iF1 = iF0 + TOT;
    int* iF2 = iF1 + TOT;
    int* iF3 = iF2 + TOT;
    float* dS0 = (float*)(iF3 + TOT);
    float* dF0 = dS0 + TOT;
    float4* partials = (float4*)(dF0 + TOT);
    size_t need = 1310720 + (size_t)9 * 65536 + 256;   // ~1.9 MB

    pack_kernel<<<(2 * TOT + 255) / 256, 256, 0, stream>>>(gts, preds, pkG, pkP);

    if (ws_size >= need) {
        sort_kernel<<<8, 1024, 0, stream>>>(pkG, pkP, sx, si, xsb);

        search_kernel<0><<<256, 256, 0, stream>>>(sx, si, xsb,
            nullptr, nullptr, nullptr, nullptr, nullptr, nullptr,
            dS0, iS0, dF0, iF0, 1);
        search_kernel<1><<<256, 256, 0, stream>>>(sx, si, xsb,
            iS0, nullptr, nullptr, iF0, nullptr, nullptr,
            nullptr, iS1, nullptr, iF1, 1);
        search_kernel<2><<<256, 256, 0, stream>>>(sx, si, xsb,
            iS0, iS1, nullptr, iF0, iF1, nullptr,
            nullptr, iS2, nullptr, iF2, 1);
        search_kernel<3><<<128, 256, 0, stream>>>(sx, si, xsb,
            iS0, iS1, iS2, iF0, iF1, iF2,
            nullptr, nullptr, nullptr, iF3, 0);
    } else {
        round_full_kernel<0><<<2048, 256, 0, stream>>>(pkG, pkP,
            nullptr, nullptr, nullptr, nullptr, nullptr, nullptr,
            dS0, iS0, dF0, iF0, 1);
        round_full_kernel<1><<<2048, 256, 0, stream>>>(pkG, pkP,
            iS0, nullptr, nullptr, iF0, nullptr, nullptr,
            nullptr, iS1, nullptr, iF1, 1);
        round_full_kernel<2><<<2048, 256, 0, stream>>>(pkG, pkP,
            iS0, iS1, nullptr, iF0, iF1, nullptr,
            nullptr, iS2, nullptr, iF2, 1);
        round_full_kernel<3><<<1024, 256, 0, stream>>>(pkG, pkP,
            iS0, iS1, iS2, iF0, iF1, iF2,
            nullptr, nullptr, nullptr, iF3, 0);
    }

    normal_kernel<<<16, 256, 0, stream>>>(preds, normals, dS0, dF0,
                                          iF0, iF1, iF2, iF3, partials);
    final_kernel<<<1, 64, 0, stream>>>(partials, out);
}

// Round 12
// 588.172 us; speedup vs baseline: 8.0945x; 8.0945x over previous
//
#include <hip/hip_runtime.h>
#include <hip/hip_bf16.h>
#include <float.h>
#include <stdint.h>

// Problem constants (fixed by setup_inputs): B=4, N=M=4096, D=3.
#define BATCH 4
#define NPTS  4096
#define TOT   (BATCH * NPTS)   // 16384

// ---------------------------------------------------------------------------
// Kernel 1: pack points into float4 {x, y, z, |p|^2}.
// rr is x*x + y*y + z*z left-to-right, matching jnp.sum(x*x, -1).
// ---------------------------------------------------------------------------
__global__ __launch_bounds__(256) void pack_kernel(
    const float* __restrict__ gts, const float* __restrict__ preds,
    float4* __restrict__ pkG, float4* __restrict__ pkP)
{
    int i = blockIdx.x * blockDim.x + threadIdx.x;   // 0 .. 2*TOT-1
    if (i >= 2 * TOT) return;
    const float* src = (i < TOT) ? gts : preds;
    float4* dst      = (i < TOT) ? pkG : pkP;
    int k            = (i < TOT) ? i : i - TOT;
    float x = src[3 * k + 0];
    float y = src[3 * k + 1];
    float z = src[3 * k + 2];
    float rr = __fadd_rn(__fadd_rn(__fmul_rn(x, x), __fmul_rn(y, y)), __fmul_rn(z, z));
    dst[k] = make_float4(x, y, z, rr);
}

// ---------------------------------------------------------------------------
// Kernel 2: per-(side,batch) bitonic sort by x (8 blocks, 1024 threads, LDS).
// 64-bit keys {monotone_bits(x) << 32 | idx} -> total order, deterministic.
// Outputs: sx (sorted float4), si (original batch-local idx), xs (sorted x).
// Layout: [side(2)][batch(4)][4096], side 0 = gts, side 1 = preds.
// (Verified in R11 — unchanged.)
// ---------------------------------------------------------------------------
__global__ __launch_bounds__(1024) void sort_kernel(
    const float4* __restrict__ pkG, const float4* __restrict__ pkP,
    float4* __restrict__ sx, int* __restrict__ si, float* __restrict__ xs)
{
    __shared__ unsigned long long keys[NPTS];   // 32 KB
    int side = blockIdx.x >> 2;
    int b = blockIdx.x & 3;
    const float4* src = (side ? pkP : pkG) + (b << 12);
    for (int t = threadIdx.x; t < NPTS; t += 1024) {
        unsigned u = __float_as_uint(src[t].x);
        u = (u & 0x80000000u) ? ~u : (u | 0x80000000u);   // monotone map
        keys[t] = ((unsigned long long)u << 32) | (unsigned)t;
    }
    __syncthreads();
    for (int k = 2; k <= NPTS; k <<= 1) {
        for (int j = k >> 1; j > 0; j >>= 1) {
            for (int t = threadIdx.x; t < NPTS; t += 1024) {
                int ixj = t ^ j;
                if (ixj > t) {
                    unsigned long long a = keys[t], c = keys[ixj];
                    bool up = (t & k) == 0;
                    if (up ? (a > c) : (a < c)) { keys[t] = c; keys[ixj] = a; }
                }
            }
            __syncthreads();
        }
    }
    int base = (int)blockIdx.x << 12;
    for (int t = threadIdx.x; t < NPTS; t += 1024) {
        int orig = (int)(unsigned)(keys[t] & 0xFFFFFFFFu);
        float4 v = src[orig];
        sx[base + t] = v;
        si[base + t] = orig;
        xs[base + t] = v.x;
    }
}

// ---------------------------------------------------------------------------
// Rounds 0-3: sorted-window argmin, WAVE-PARALLEL chunked version of the
// R11-verified logic. One wave per (direction, own point). Per chunk: lanes
// 0-31 take the next 32 left candidates, lanes 32-63 the next 32 right
// (coalesced — sorted arrays are contiguous); if only one side is active all
// 64 lanes take it. d uses the EXACT verified formula; lex (d, j) updates ==
// numpy first-argmin tie-break (scan-order independent; evaluating extra
// in-chunk candidates is a superset -> exact). After each chunk the wave
// lex-min is shared (butterfly) and a side stops when its next candidate has
// fl(dx)^2 > best + MARGIN (dx monotone along sorted x; dx^2 lower-bounds
// d_true; |fl(d)-d_true| <= ~4e-5 << MARGIN=1e-3, best only decreases ->
// no candidate that could achieve or tie the minimal computed d is pruned).
// Exclusions (round R): j == e_t OR rev_t[j] == ownIn for t < R, inline.
// All-excluded row -> best stays FLT_MAX, bs=inf -> full safe scan, bestj=0
// (= numpy argmin of an all-max row).
// ---------------------------------------------------------------------------
template<int R>
__global__ __launch_bounds__(256) void search_kernel(
    const float4* __restrict__ sx, const int* __restrict__ si,
    const float* __restrict__ xs,
    const int* __restrict__ is0, const int* __restrict__ is1, const int* __restrict__ is2,
    const int* __restrict__ if0, const int* __restrict__ if1, const int* __restrict__ if2,
    float* __restrict__ dS, int* __restrict__ iS,
    float* __restrict__ dF, int* __restrict__ iF,
    int do_rows)
{
    int wid  = blockIdx.x * 4 + (threadIdx.x >> 6);
    int lane = threadIdx.x & 63;
    int half = do_rows ? TOT : 0;
    bool isRow = wid < half;             // s2f: own = gts, other = preds
    int t = isRow ? wid : wid - half;    // (b, sorted own position p)
    int b = t >> 12, p = t & (NPTS - 1);
    int obase = b << 12;

    int ownSide = isRow ? 0 : 1;
    int obOwn = ((ownSide << 2) | b) << 12;
    int obOth = (((1 - ownSide) << 2) | b) << 12;
    const float4* sOwn = sx + obOwn;
    const int*    iOwn = si + obOwn;
    const float4* sOth = sx + obOth;
    const int*    iOth = si + obOth;
    const float*  xOth = xs + obOth;

    float4 ow = sOwn[p];
    int ownIn = iOwn[p];

    int e0 = -1, e1 = -1, e2 = -1;
    if (R > 0) e0 = (isRow ? is0 : if0)[obase + ownIn];
    if (R > 1) e1 = (isRow ? is1 : if1)[obase + ownIn];
    if (R > 2) e2 = (isRow ? is2 : if2)[obase + ownIn];
    const int* r0 = (R > 0) ? (isRow ? if0 : is0) + obase : nullptr;
    const int* r1 = (R > 1) ? (isRow ? if1 : is1) + obase : nullptr;
    const int* r2 = (R > 2) ? (isRow ? if2 : is2) + obase : nullptr;

    // lower bound of own.x in sorted-other x (wave-uniform, broadcast loads)
    float bx = ow.x;
    int lo = 0, hi = NPTS;
    while (lo < hi) {
        int mid = (lo + hi) >> 1;
        if (xOth[mid] < bx) lo = mid + 1; else hi = mid;
    }

    int L  = lo - 1;                 // next unevaluated left position
    int Rp = lo;                     // next unevaluated right position
    bool leftAct  = (L >= 0);
    bool rightAct = (Rp < NPTS);
    float best = FLT_MAX; int bestj = 0;
    const float MARGIN = 1e-3f;

    while (leftAct || rightAct) {
        bool bothAct = leftAct && rightAct;
        int pos; bool doEval;
        if (bothAct) {
            bool isL = lane < 32;
            pos = isL ? (L - lane) : (Rp + (lane - 32));
            doEval = isL ? (pos >= 0) : (pos < NPTS);
        } else if (leftAct) {
            pos = L - lane;  doEval = pos >= 0;
        } else {
            pos = Rp + lane; doEval = pos < NPTS;
        }
        if (doEval) {
            float4 q = sOth[pos];
            int j = iOth[pos];
            float zz = __fadd_rn(__fadd_rn(__fmul_rn(ow.x, q.x),
                                           __fmul_rn(ow.y, q.y)),
                                 __fmul_rn(ow.z, q.z));
            float d = __fmaf_rn(-2.0f, zz, __fadd_rn(ow.w, q.w));
            bool ex = false;
            if (R > 0) ex = (j == e0) || (r0[j] == ownIn);
            if (R > 1) ex = ex || (j == e1) || (r1[j] == ownIn);
            if (R > 2) ex = ex || (j == e2) || (r2[j] == ownIn);
            if (!ex && (d < best || (d == best && j < bestj))) {
                best = d; bestj = j;
            }
        }
        // advance frontiers past what this chunk covered
        if (bothAct) { L -= 32; Rp += 32; }
        else if (leftAct) { L -= 64; }
        else { Rp += 64; }

        // wave lex-min of (best, bestj) -> every lane holds the running min
        #pragma unroll
        for (int off = 1; off < 64; off <<= 1) {
            float v2 = __shfl_xor(best, off);
            int   i2 = __shfl_xor(bestj, off);
            if (v2 < best || (v2 == best && i2 < bestj)) { best = v2; bestj = i2; }
        }
        float bs = best + MARGIN;

        if (leftAct) {
            if (L < 0) leftAct = false;
            else {
                float dxl = __fsub_rn(bx, xOth[L]);          // >= 0, monotone
                if (__fmul_rn(dxl, dxl) > bs) leftAct = false;
            }
        }
        if (rightAct) {
            if (Rp >= NPTS) rightAct = false;
            else {
                float dxr = __fsub_rn(xOth[Rp], bx);         // >= 0, monotone
                if (__fmul_rn(dxr, dxr) > bs) rightAct = false;
            }
        }
    }

    if (lane == 0) {
        if (isRow) { iS[obase + ownIn] = bestj; if (R == 0) dS[obase + ownIn] = best; }
        else       { iF[obase + ownIn] = bestj; if (R == 0) dF[obase + ownIn] = best; }
    }
}

// ---------------------------------------------------------------------------
// Fallback full-rescan kernel (verified in R4) — used only if ws too small.
// ---------------------------------------------------------------------------
template<int R>
__global__ __launch_bounds__(256) void round_full_kernel(
    const float4* __restrict__ pkG, const float4* __restrict__ pkP,
    const int* __restrict__ is0, const int* __restrict__ is1, const int* __restrict__ is2,
    const int* __restrict__ if0, const int* __restrict__ if1, const int* __restrict__ if2,
    float* __restrict__ dS, int* __restrict__ iS,
    float* __restrict__ dF, int* __restrict__ iF,
    int do_rows)
{
    int half    = do_rows ? (gridDim.x >> 1) : gridDim.x;
    bool isRow  = do_rows && ((int)blockIdx.x < half);
    int dirBlk  = isRow ? blockIdx.x : (blockIdx.x - (do_rows ? half : 0));

    const float4* own = isRow ? pkG : pkP;
    const float4* oth = isRow ? pkP : pkG;
    const int* exOwn0 = isRow ? is0 : if0;
    const int* exOwn1 = isRow ? is1 : if1;
    const int* exOwn2 = isRow ? is2 : if2;
    const int* exOth0 = isRow ? if0 : is0;
    const int* exOth1 = isRow ? if1 : is1;
    const int* exOth2 = isRow ? if2 : is2;
    float* dOut = isRow ? dS : dF;
    int*   iOut = isRow ? iS : iF;

    int lane = threadIdx.x & 63;
    int wave = threadIdx.x >> 6;
    int ownBase = dirBlk * 16 + wave * 4;
    int b = ownBase >> 12;
    int obase = b << 12;

    float ox[4], oy[4], oz[4], orr[4];
    int ownIn[4];
    int oe0[4], oe1[4], oe2[4];
    #pragma unroll
    for (int r = 0; r < 4; ++r) {
        float4 p = own[ownBase + r];
        ox[r] = p.x; oy[r] = p.y; oz[r] = p.z; orr[r] = p.w;
        ownIn[r] = (ownBase & (NPTS - 1)) + r;
        oe0[r] = 0; oe1[r] = 0; oe2[r] = 0;
        if (R > 0) oe0[r] = exOwn0[ownBase + r];
        if (R > 1) oe1[r] = exOwn1[ownBase + r];
        if (R > 2) oe2[r] = exOwn2[ownBase + r];
    }

    float best[4]; int bidx[4];
    #pragma unroll
    for (int r = 0; r < 4; ++r) { best[r] = FLT_MAX; bidx[r] = 0; }

    for (int j = lane; j < NPTS; j += 64) {
        float4 q = oth[obase + j];
        int eo0 = 0, eo1 = 0, eo2 = 0;
        if (R > 0) eo0 = exOth0[obase + j];
        if (R > 1) eo1 = exOth1[obase + j];
        if (R > 2) eo2 = exOth2[obase + j];
        #pragma unroll
        for (int r = 0; r < 4; ++r) {
            float zz = __fadd_rn(__fadd_rn(__fmul_rn(ox[r], q.x),
                                           __fmul_rn(oy[r], q.y)),
                                 __fmul_rn(oz[r], q.z));
            float d = __fmaf_rn(-2.0f, zz, __fadd_rn(orr[r], q.w));
            bool ex = false;
            if (R > 0) ex = ex || (j == oe0[r]) || (eo0 == ownIn[r]);
            if (R > 1) ex = ex || (j == oe1[r]) || (eo1 == ownIn[r]);
            if (R > 2) ex = ex || (j == oe2[r]) || (eo2 == ownIn[r]);
            if (ex) d = FLT_MAX;
            if (d < best[r]) { best[r] = d; bidx[r] = j; }
        }
    }

    #pragma unroll
    for (int r = 0; r < 4; ++r) {
        float v = best[r]; int ix = bidx[r];
        #pragma unroll
        for (int off = 32; off > 0; off >>= 1) {
            float v2 = __shfl_xor(v, off);
            int   i2 = __shfl_xor(ix, off);
            if (v2 < v || (v2 == v && i2 < ix)) { v = v2; ix = i2; }
        }
        if (lane == 0) {
            iOut[ownBase + r] = ix;
            if (dOut) dOut[ownBase + r] = v;
        }
    }
}

// ---------------------------------------------------------------------------
// Per-(batch, segment) partial sums (unchanged, verified).
// ---------------------------------------------------------------------------
__global__ __launch_bounds__(256) void normal_kernel(
    const float* __restrict__ preds, const float* __restrict__ normals,
    const float* __restrict__ dS, const float* __restrict__ dF,
    const int* __restrict__ if0, const int* __restrict__ if1,
    const int* __restrict__ if2, const int* __restrict__ if3,
    float4* __restrict__ partials)
{
    int b   = blockIdx.x >> 2;
    int seg = blockIdx.x & 3;
    int t   = threadIdx.x;

    const float* pp = preds + (size_t)b * NPTS * 3;
    float champ = 0.f, s1 = 0.f, s2 = 0.f, s3 = 0.f;

    for (int it = 0; it < 4; ++it) {
        int m  = seg * 1024 + it * 256 + t;
        int gi = b * NPTS + m;
        champ += dF[gi] + dS[gi];

        int i0 = if0[gi];
        float p0x = pp[3 * i0 + 0], p0y = pp[3 * i0 + 1], p0z = pp[3 * i0 + 2];
        float nx = normals[3 * gi + 0], ny = normals[3 * gi + 1], nz = normals[3 * gi + 2];

        int iA = if1[gi];
        s1 += (p0x - pp[3 * iA + 0]) * nx + (p0y - pp[3 * iA + 1]) * ny + (p0z - pp[3 * iA + 2]) * nz;
        int iB = if2[gi];
        s2 += (p0x - pp[3 * iB + 0]) * nx + (p0y - pp[3 * iB + 1]) * ny + (p0z - pp[3 * iB + 2]) * nz;
        int iC = if3[gi];
        s3 += (p0x - pp[3 * iC + 0]) * nx + (p0y - pp[3 * iC + 1]) * ny + (p0z - pp[3 * iC + 2]) * nz;
    }

    #pragma unroll
    for (int off = 32; off > 0; off >>= 1) {
        champ += __shfl_xor(champ, off);
        s1    += __shfl_xor(s1, off);
        s2    += __shfl_xor(s2, off);
        s3    += __shfl_xor(s3, off);
    }
    __shared__ float4 red[4];
    int wave = t >> 6, lane = t & 63;
    if (lane == 0) red[wave] = make_float4(champ, s1, s2, s3);
    __syncthreads();
    if (t == 0) {
        float4 a = red[0];
        for (int w = 1; w < 4; ++w) {
            a.x += red[w].x; a.y += red[w].y; a.z += red[w].z; a.w += red[w].w;
        }
        partials[blockIdx.x] = a;
    }
}

__global__ void final_kernel(const float4* __restrict__ partials, float* __restrict__ out)
{
    if (blockIdx.x == 0 && threadIdx.x == 0) {
        float champ = 0.f;
        float s[BATCH][3];
        for (int b = 0; b < BATCH; ++b) for (int k = 0; k < 3; ++k) s[b][k] = 0.f;
        for (int blk = 0; blk < 16; ++blk) {
            float4 p = partials[blk];
            int b = blk >> 2;
            champ   += p.x;
            s[b][0] += p.y;
            s[b][1] += p.z;
            s[b][2] += p.w;
        }
        float nl = 0.f;
        for (int k = 0; k < 3; ++k)
            for (int b = 0; b < BATCH; ++b)
                nl += fabsf(s[b][k]);
        out[0] = 1.0f + champ + 10.0f * nl;
    }
}

// ---------------------------------------------------------------------------
// Launch. Workspace (~1.9 MB):
//   pkG | pkP (256 KB ea) | sx (512 KB) | si (128 KB) | xs (128 KB) |
//   iS0..iS2, iF0..iF3 (7 x 64 KB) | dS0 | dF0 | partials
// Fallback: verified full-rescan chain if ws too small.
// ---------------------------------------------------------------------------
extern "C" void kernel_launch(void* const* d_in, const int* in_sizes, int n_in,
                              void* d_out, int out_size, void* d_ws, size_t ws_size,
                              hipStream_t stream) {
    const float* gts     = (const float*)d_in[0];
    const float* preds   = (const float*)d_in[1];
    const float* normals = (const float*)d_in[2];
    float* out = (float*)d_out;

    char* ws = (char*)d_ws;
    float4* pkG = (float4*)ws;
    float4* pkP = (float4*)(ws + 262144);
    float4* sx  = (float4*)(ws + 524288);
    int*    si  = (int*)(ws + 1048576);
    float*  xsb = (float*)(ws + 1179648);
    int* iS0 = (int*)(ws + 1310720);
    int* iS1 = iS0 + TOT;
    int* iS2 = iS1 + TOT;
    int* iF0 = iS2 + TOT;
    int* iF1 = iF0 + TOT;
    int* iF2 = iF1 + TOT;
    int* iF3 = iF2 + TOT;
    float* dS0 = (float*)(iF3 + TOT);
    float* dF0 = dS0 + TOT;
    float4* partials = (float4*)(dF0 + TOT);
    size_t need = 1310720 + (size_t)9 * 65536 + 256;   // ~1.9 MB

    pack_kernel<<<(2 * TOT + 255) / 256, 256, 0, stream>>>(gts, preds, pkG, pkP);

    if (ws_size >= need) {
        sort_kernel<<<8, 1024, 0, stream>>>(pkG, pkP, sx, si, xsb);

        // one wave per (direction, own point): rounds 0-2 -> 2*TOT waves,
        // round 3 (cols only) -> TOT waves; 4 waves per 256-thread block.
        search_kernel<0><<<2 * TOT / 4, 256, 0, stream>>>(sx, si, xsb,
            nullptr, nullptr, nullptr, nullptr, nullptr, nullptr,
            dS0, iS0, dF0, iF0, 1);
        search_kernel<1><<<2 * TOT / 4, 256, 0, stream>>>(sx, si, xsb,
            iS0, nullptr, nullptr, iF0, nullptr, nullptr,
            nullptr, iS1, nullptr, iF1, 1);
        search_kernel<2><<<2 * TOT / 4, 256, 0, stream>>>(sx, si, xsb,
            iS0, iS1, nullptr, iF0, iF1, nullptr,
            nullptr, iS2, nullptr, iF2, 1);
        search_kernel<3><<<TOT / 4, 256, 0, stream>>>(sx, si, xsb,
            iS0, iS1, iS2, iF0, iF1, iF2,
            nullptr, nullptr, nullptr, iF3, 0);
    } else {
        round_full_kernel<0><<<2048, 256, 0, stream>>>(pkG, pkP,
            nullptr, nullptr, nullptr, nullptr, nullptr, nullptr,
            dS0, iS0, dF0, iF0, 1);
        round_full_kernel<1><<<2048, 256, 0, stream>>>(pkG, pkP,
            iS0, nullptr, nullptr, iF0, nullptr, nullptr,
            nullptr, iS1, nullptr, iF1, 1);
        round_full_kernel<2><<<2048, 256, 0, stream>>>(pkG, pkP,
            iS0, iS1, nullptr, iF0, iF1, nullptr,
            nullptr, iS2, nullptr, iF2, 1);
        round_full_kernel<3><<<1024, 256, 0, stream>>>(pkG, pkP,
            iS0, iS1, iS2, iF0, iF1, iF2,
            nullptr, nullptr, nullptr, iF3, 0);
    }

    normal_kernel<<<16, 256, 0, stream>>>(preds, normals, dS0, dF0,
                                          iF0, iF1, iF2, iF3, partials);
    final_kernel<<<1, 64, 0, stream>>>(partials, out);
}

// Round 13
// 531.173 us; speedup vs baseline: 8.9631x; 1.1073x over previous
//
#include <hip/hip_runtime.h>
#include <hip/hip_bf16.h>
#include <float.h>
#include <stdint.h>

// Problem constants (fixed by setup_inputs): B=4, N=M=4096, D=3.
#define BATCH 4
#define NPTS  4096
#define TOT   (BATCH * NPTS)   // 16384

// ---------------------------------------------------------------------------
// Kernel 1: pack points into float4 {x, y, z, |p|^2}.
// rr is x*x + y*y + z*z left-to-right, matching jnp.sum(x*x, -1).
// ---------------------------------------------------------------------------
__global__ __launch_bounds__(256) void pack_kernel(
    const float* __restrict__ gts, const float* __restrict__ preds,
    float4* __restrict__ pkG, float4* __restrict__ pkP)
{
    int i = blockIdx.x * blockDim.x + threadIdx.x;   // 0 .. 2*TOT-1
    if (i >= 2 * TOT) return;
    const float* src = (i < TOT) ? gts : preds;
    float4* dst      = (i < TOT) ? pkG : pkP;
    int k            = (i < TOT) ? i : i - TOT;
    float x = src[3 * k + 0];
    float y = src[3 * k + 1];
    float z = src[3 * k + 2];
    float rr = __fadd_rn(__fadd_rn(__fmul_rn(x, x), __fmul_rn(y, y)), __fmul_rn(z, z));
    dst[k] = make_float4(x, y, z, rr);
}

// ---------------------------------------------------------------------------
// Kernel 2: per-(side,batch) bitonic sort by x (8 blocks, 1024 threads, LDS).
// 64-bit keys {monotone_bits(x) << 32 | idx} -> total order, deterministic.
// Outputs: sx (sorted float4), si (original batch-local idx), xs (sorted x).
// Layout: [side(2)][batch(4)][4096], side 0 = gts, side 1 = preds.
// (Verified in R11/R12 — unchanged.)
// ---------------------------------------------------------------------------
__global__ __launch_bounds__(1024) void sort_kernel(
    const float4* __restrict__ pkG, const float4* __restrict__ pkP,
    float4* __restrict__ sx, int* __restrict__ si, float* __restrict__ xs)
{
    __shared__ unsigned long long keys[NPTS];   // 32 KB
    int side = blockIdx.x >> 2;
    int b = blockIdx.x & 3;
    const float4* src = (side ? pkP : pkG) + (b << 12);
    for (int t = threadIdx.x; t < NPTS; t += 1024) {
        unsigned u = __float_as_uint(src[t].x);
        u = (u & 0x80000000u) ? ~u : (u | 0x80000000u);   // monotone map
        keys[t] = ((unsigned long long)u << 32) | (unsigned)t;
    }
    __syncthreads();
    for (int k = 2; k <= NPTS; k <<= 1) {
        for (int j = k >> 1; j > 0; j >>= 1) {
            for (int t = threadIdx.x; t < NPTS; t += 1024) {
                int ixj = t ^ j;
                if (ixj > t) {
                    unsigned long long a = keys[t], c = keys[ixj];
                    bool up = (t & k) == 0;
                    if (up ? (a > c) : (a < c)) { keys[t] = c; keys[ixj] = a; }
                }
            }
            __syncthreads();
        }
    }
    int base = (int)blockIdx.x << 12;
    for (int t = threadIdx.x; t < NPTS; t += 1024) {
        int orig = (int)(unsigned)(keys[t] & 0xFFFFFFFFu);
        float4 v = src[orig];
        sx[base + t] = v;
        si[base + t] = orig;
        xs[base + t] = v.x;
    }
}

// ---------------------------------------------------------------------------
// Rounds 0-3: sorted-window argmin, LOW-SERIAL-DEPTH version.
// One wave per (direction, own point):
//  1. two-ballot position find: lane k probes xOth[64k] (L1-hot), ballot ->
//     coarse bucket; coalesced 64-wide probe + ballot -> exact lower bound.
//  2. fixed 256-candidate window centered on lo: 4 independent coalesced
//     chunks, per-lane lex (d, j) updates; ONE butterfly reduce.
//  3. frontier checks: side survives only if its next unevaluated position
//     has fl(dx)^2 <= best + MARGIN; usually both fail -> done.
//  4. rare continuation: the EXACT R12-verified chunked loop, pre-seeded.
// Exactness: evaluating a superset is exact (lex updates scan-order-free);
// dx^2 lower-bounds d_true, |fl(d)-d_true| <= ~4e-5 << MARGIN=1e-3, best
// only decreases -> no candidate that could achieve or tie the minimal
// computed d is pruned. Exclusions tested inline. All-excluded row: best
// stays FLT_MAX -> frontier checks never prune -> full scan -> bestj = 0
// (= numpy argmin of an all-max row).
// ---------------------------------------------------------------------------
template<int R>
__global__ __launch_bounds__(256) void search_kernel(
    const float4* __restrict__ sx, const int* __restrict__ si,
    const float* __restrict__ xs,
    const int* __restrict__ is0, const int* __restrict__ is1, const int* __restrict__ is2,
    const int* __restrict__ if0, const int* __restrict__ if1, const int* __restrict__ if2,
    float* __restrict__ dS, int* __restrict__ iS,
    float* __restrict__ dF, int* __restrict__ iF,
    int do_rows)
{
    int wid  = blockIdx.x * 4 + (threadIdx.x >> 6);
    int lane = threadIdx.x & 63;
    int half = do_rows ? TOT : 0;
    bool isRow = wid < half;             // s2f: own = gts, other = preds
    int t = isRow ? wid : wid - half;    // (b, sorted own position p)
    int b = t >> 12, p = t & (NPTS - 1);
    int obase = b << 12;

    int ownSide = isRow ? 0 : 1;
    int obOwn = ((ownSide << 2) | b) << 12;
    int obOth = (((1 - ownSide) << 2) | b) << 12;
    const float4* sOwn = sx + obOwn;
    const int*    iOwn = si + obOwn;
    const float4* sOth = sx + obOth;
    const int*    iOth = si + obOth;
    const float*  xOth = xs + obOth;

    float4 ow = sOwn[p];
    int ownIn = iOwn[p];

    int e0 = -1, e1 = -1, e2 = -1;
    if (R > 0) e0 = (isRow ? is0 : if0)[obase + ownIn];
    if (R > 1) e1 = (isRow ? is1 : if1)[obase + ownIn];
    if (R > 2) e2 = (isRow ? is2 : if2)[obase + ownIn];
    const int* r0 = (R > 0) ? (isRow ? if0 : is0) + obase : nullptr;
    const int* r1 = (R > 1) ? (isRow ? if1 : is1) + obase : nullptr;
    const int* r2 = (R > 2) ? (isRow ? if2 : is2) + obase : nullptr;

    // ---- two-ballot lower bound of own.x in sorted-other x
    float bx = ow.x;
    float sv1 = xOth[lane << 6];                       // samples 0,64,...,4032
    unsigned long long m1 = __ballot(sv1 < bx);
    int cnt1 = __popcll(m1);
    int base2 = (cnt1 > 0 ? cnt1 - 1 : 0) << 6;        // <= 4032
    float sv2 = xOth[base2 + lane];                    // coalesced
    unsigned long long m2 = __ballot(sv2 < bx);
    int lo = base2 + __popcll(m2);                     // == lower_bound

    // ---- fixed 256-candidate window centered on lo
    const int W = 256;
    int start = lo - (W / 2);
    if (start < 0) start = 0;
    if (start > NPTS - W) start = NPTS - W;

    float best = FLT_MAX; int bestj = 0;
    #pragma unroll
    for (int c = 0; c < 4; ++c) {
        int pos = start + (c << 6) + lane;             // coalesced
        float4 q = sOth[pos];
        int j = iOth[pos];
        float zz = __fadd_rn(__fadd_rn(__fmul_rn(ow.x, q.x),
                                       __fmul_rn(ow.y, q.y)),
                             __fmul_rn(ow.z, q.z));
        float d = __fmaf_rn(-2.0f, zz, __fadd_rn(ow.w, q.w));
        bool ex = false;
        if (R > 0) ex = (j == e0) || (r0[j] == ownIn);
        if (R > 1) ex = ex || (j == e1) || (r1[j] == ownIn);
        if (R > 2) ex = ex || (j == e2) || (r2[j] == ownIn);
        if (!ex && (d < best || (d == best && j < bestj))) { best = d; bestj = j; }
    }
    #pragma unroll
    for (int off = 1; off < 64; off <<= 1) {
        float v2 = __shfl_xor(best, off);
        int   i2 = __shfl_xor(bestj, off);
        if (v2 < best || (v2 == best && i2 < bestj)) { best = v2; bestj = i2; }
    }

    // ---- frontier checks; rare continuation (exact R12-verified loop)
    const float MARGIN = 1e-3f;
    float bs = best + MARGIN;
    int L  = start - 1;
    int Rp = start + W;
    bool leftAct  = (L >= 0)    && !(__fmul_rn(__fsub_rn(bx, xOth[L]),  __fsub_rn(bx, xOth[L]))  > bs);
    bool rightAct = (Rp < NPTS) && !(__fmul_rn(__fsub_rn(xOth[Rp], bx), __fsub_rn(xOth[Rp], bx)) > bs);

    while (leftAct || rightAct) {
        bool bothAct = leftAct && rightAct;
        int pos; bool doEval;
        if (bothAct) {
            bool isL = lane < 32;
            pos = isL ? (L - lane) : (Rp + (lane - 32));
            doEval = isL ? (pos >= 0) : (pos < NPTS);
        } else if (leftAct) {
            pos = L - lane;  doEval = pos >= 0;
        } else {
            pos = Rp + lane; doEval = pos < NPTS;
        }
        if (doEval) {
            float4 q = sOth[pos];
            int j = iOth[pos];
            float zz = __fadd_rn(__fadd_rn(__fmul_rn(ow.x, q.x),
                                           __fmul_rn(ow.y, q.y)),
                                 __fmul_rn(ow.z, q.z));
            float d = __fmaf_rn(-2.0f, zz, __fadd_rn(ow.w, q.w));
            bool ex = false;
            if (R > 0) ex = (j == e0) || (r0[j] == ownIn);
            if (R > 1) ex = ex || (j == e1) || (r1[j] == ownIn);
            if (R > 2) ex = ex || (j == e2) || (r2[j] == ownIn);
            if (!ex && (d < best || (d == best && j < bestj))) { best = d; bestj = j; }
        }
        if (bothAct) { L -= 32; Rp += 32; }
        else if (leftAct) { L -= 64; }
        else { Rp += 64; }

        #pragma unroll
        for (int off = 1; off < 64; off <<= 1) {
            float v2 = __shfl_xor(best, off);
            int   i2 = __shfl_xor(bestj, off);
            if (v2 < best || (v2 == best && i2 < bestj)) { best = v2; bestj = i2; }
        }
        bs = best + MARGIN;

        if (leftAct) {
            if (L < 0) leftAct = false;
            else {
                float dxl = __fsub_rn(bx, xOth[L]);
                if (__fmul_rn(dxl, dxl) > bs) leftAct = false;
            }
        }
        if (rightAct) {
            if (Rp >= NPTS) rightAct = false;
            else {
                float dxr = __fsub_rn(xOth[Rp], bx);
                if (__fmul_rn(dxr, dxr) > bs) rightAct = false;
            }
        }
    }

    if (lane == 0) {
        if (isRow) { iS[obase + ownIn] = bestj; if (R == 0) dS[obase + ownIn] = best; }
        else       { iF[obase + ownIn] = bestj; if (R == 0) dF[obase + ownIn] = best; }
    }
}

// ---------------------------------------------------------------------------
// Fallback full-rescan kernel (verified in R4) — used only if ws too small.
// ---------------------------------------------------------------------------
template<int R>
__global__ __launch_bounds__(256) void round_full_kernel(
    const float4* __restrict__ pkG, const float4* __restrict__ pkP,
    const int* __restrict__ is0, const int* __restrict__ is1, const int* __restrict__ is2,
    const int* __restrict__ if0, const int* __restrict__ if1, const int* __restrict__ if2,
    float* __restrict__ dS, int* __restrict__ iS,
    float* __restrict__ dF, int* __restrict__ iF,
    int do_rows)
{
    int half    = do_rows ? (gridDim.x >> 1) : gridDim.x;
    bool isRow  = do_rows && ((int)blockIdx.x < half);
    int dirBlk  = isRow ? blockIdx.x : (blockIdx.x - (do_rows ? half : 0));

    const float4* own = isRow ? pkG : pkP;
    const float4* oth = isRow ? pkP : pkG;
    const int* exOwn0 = isRow ? is0 : if0;
    const int* exOwn1 = isRow ? is1 : if1;
    const int* exOwn2 = isRow ? is2 : if2;
    const int* exOth0 = isRow ? if0 : is0;
    const int* exOth1 = isRow ? if1 : is1;
    const int* exOth2 = isRow ? if2 : is2;
    float* dOut = isRow ? dS : dF;
    int*   iOut = isRow ? iS : iF;

    int lane = threadIdx.x & 63;
    int wave = threadIdx.x >> 6;
    int ownBase = dirBlk * 16 + wave * 4;
    int b = ownBase >> 12;
    int obase = b << 12;

    float ox[4], oy[4], oz[4], orr[4];
    int ownIn[4];
    int oe0[4], oe1[4], oe2[4];
    #pragma unroll
    for (int r = 0; r < 4; ++r) {
        float4 p = own[ownBase + r];
        ox[r] = p.x; oy[r] = p.y; oz[r] = p.z; orr[r] = p.w;
        ownIn[r] = (ownBase & (NPTS - 1)) + r;
        oe0[r] = 0; oe1[r] = 0; oe2[r] = 0;
        if (R > 0) oe0[r] = exOwn0[ownBase + r];
        if (R > 1) oe1[r] = exOwn1[ownBase + r];
        if (R > 2) oe2[r] = exOwn2[ownBase + r];
    }

    float best[4]; int bidx[4];
    #pragma unroll
    for (int r = 0; r < 4; ++r) { best[r] = FLT_MAX; bidx[r] = 0; }

    for (int j = lane; j < NPTS; j += 64) {
        float4 q = oth[obase + j];
        int eo0 = 0, eo1 = 0, eo2 = 0;
        if (R > 0) eo0 = exOth0[obase + j];
        if (R > 1) eo1 = exOth1[obase + j];
        if (R > 2) eo2 = exOth2[obase + j];
        #pragma unroll
        for (int r = 0; r < 4; ++r) {
            float zz = __fadd_rn(__fadd_rn(__fmul_rn(ox[r], q.x),
                                           __fmul_rn(oy[r], q.y)),
                                 __fmul_rn(oz[r], q.z));
            float d = __fmaf_rn(-2.0f, zz, __fadd_rn(orr[r], q.w));
            bool ex = false;
            if (R > 0) ex = ex || (j == oe0[r]) || (eo0 == ownIn[r]);
            if (R > 1) ex = ex || (j == oe1[r]) || (eo1 == ownIn[r]);
            if (R > 2) ex = ex || (j == oe2[r]) || (eo2 == ownIn[r]);
            if (ex) d = FLT_MAX;
            if (d < best[r]) { best[r] = d; bidx[r] = j; }
        }
    }

    #pragma unroll
    for (int r = 0; r < 4; ++r) {
        float v = best[r]; int ix = bidx[r];
        #pragma unroll
        for (int off = 32; off > 0; off >>= 1) {
            float v2 = __shfl_xor(v, off);
            int   i2 = __shfl_xor(ix, off);
            if (v2 < v || (v2 == v && i2 < ix)) { v = v2; ix = i2; }
        }
        if (lane == 0) {
            iOut[ownBase + r] = ix;
            if (dOut) dOut[ownBase + r] = v;
        }
    }
}

// ---------------------------------------------------------------------------
// Per-(batch, segment) partial sums (unchanged, verified).
// ---------------------------------------------------------------------------
__global__ __launch_bounds__(256) void normal_kernel(
    const float* __restrict__ preds, const float* __restrict__ normals,
    const float* __restrict__ dS, const float* __restrict__ dF,
    const int* __restrict__ if0, const int* __restrict__ if1,
    const int* __restrict__ if2, const int* __restrict__ if3,
    float4* __restrict__ partials)
{
    int b   = blockIdx.x >> 2;
    int seg = blockIdx.x & 3;
    int t   = threadIdx.x;

    const float* pp = preds + (size_t)b * NPTS * 3;
    float champ = 0.f, s1 = 0.f, s2 = 0.f, s3 = 0.f;

    for (int it = 0; it < 4; ++it) {
        int m  = seg * 1024 + it * 256 + t;
        int gi = b * NPTS + m;
        champ += dF[gi] + dS[gi];

        int i0 = if0[gi];
        float p0x = pp[3 * i0 + 0], p0y = pp[3 * i0 + 1], p0z = pp[3 * i0 + 2];
        float nx = normals[3 * gi + 0], ny = normals[3 * gi + 1], nz = normals[3 * gi + 2];

        int iA = if1[gi];
        s1 += (p0x - pp[3 * iA + 0]) * nx + (p0y - pp[3 * iA + 1]) * ny + (p0z - pp[3 * iA + 2]) * nz;
        int iB = if2[gi];
        s2 += (p0x - pp[3 * iB + 0]) * nx + (p0y - pp[3 * iB + 1]) * ny + (p0z - pp[3 * iB + 2]) * nz;
        int iC = if3[gi];
        s3 += (p0x - pp[3 * iC + 0]) * nx + (p0y - pp[3 * iC + 1]) * ny + (p0z - pp[3 * iC + 2]) * nz;
    }

    #pragma unroll
    for (int off = 32; off > 0; off >>= 1) {
        champ += __shfl_xor(champ, off);
        s1    += __shfl_xor(s1, off);
        s2    += __shfl_xor(s2, off);
        s3    += __shfl_xor(s3, off);
    }
    __shared__ float4 red[4];
    int wave = t >> 6, lane = t & 63;
    if (lane == 0) red[wave] = make_float4(champ, s1, s2, s3);
    __syncthreads();
    if (t == 0) {
        float4 a = red[0];
        for (int w = 1; w < 4; ++w) {
            a.x += red[w].x; a.y += red[w].y; a.z += red[w].z; a.w += red[w].w;
        }
        partials[blockIdx.x] = a;
    }
}

__global__ void final_kernel(const float4* __restrict__ partials, float* __restrict__ out)
{
    if (blockIdx.x == 0 && threadIdx.x == 0) {
        float champ = 0.f;
        float s[BATCH][3];
        for (int b = 0; b < BATCH; ++b) for (int k = 0; k < 3; ++k) s[b][k] = 0.f;
        for (int blk = 0; blk < 16; ++blk) {
            float4 p = partials[blk];
            int b = blk >> 2;
            champ   += p.x;
            s[b][0] += p.y;
            s[b][1] += p.z;
            s[b][2] += p.w;
        }
        float nl = 0.f;
        for (int k = 0; k < 3; ++k)
            for (int b = 0; b < BATCH; ++b)
                nl += fabsf(s[b][k]);
        out[0] = 1.0f + champ + 10.0f * nl;
    }
}

// ---------------------------------------------------------------------------
// Launch. Workspace (~1.9 MB):
//   pkG | pkP (256 KB ea) | sx (512 KB) | si (128 KB) | xs (128 KB) |
//   iS0..iS2, iF0..iF3 (7 x 64 KB) | dS0 | dF0 | partials
// Fallback: verified full-rescan chain if ws too small.
// ---------------------------------------------------------------------------
extern "C" void kernel_launch(void* const* d_in, const int* in_sizes, int n_in,
                              void* d_out, int out_size, void* d_ws, size_t ws_size,
                              hipStream_t stream) {
    const float* gts     = (const float*)d_in[0];
    const float* preds   = (const float*)d_in[1];
    const float* normals = (const float*)d_in[2];
    float* out = (float*)d_out;

    char* ws = (char*)d_ws;
    float4* pkG = (float4*)ws;
    float4* pkP = (float4*)(ws + 262144);
    float4* sx  = (float4*)(ws + 524288);
    int*    si  = (int*)(ws + 1048576);
    float*  xsb = (float*)(ws + 1179648);
    int* iS0 = (int*)(ws + 1310720);
    int* iS1 = iS0 + TOT;
    int* iS2 = iS1 + TOT;
    int* iF0 = iS2 + TOT;
    int* iF1 = iF0 + TOT;
    int* iF2 = iF1 + TOT;
    int* iF3 = iF2 + TOT;
    float* dS0 = (float*)(iF3 + TOT);
    float* dF0 = dS0 + TOT;
    float4* partials = (float4*)(dF0 + TOT);
    size_t need = 1310720 + (size_t)9 * 65536 + 256;   // ~1.9 MB

    pack_kernel<<<(2 * TOT + 255) / 256, 256, 0, stream>>>(gts, preds, pkG, pkP);

    if (ws_size >= need) {
        sort_kernel<<<8, 1024, 0, stream>>>(pkG, pkP, sx, si, xsb);

        // one wave per (direction, own point); 4 waves per block.
        search_kernel<0><<<2 * TOT / 4, 256, 0, stream>>>(sx, si, xsb,
            nullptr, nullptr, nullptr, nullptr, nullptr, nullptr,
            dS0, iS0, dF0, iF0, 1);
        search_kernel<1><<<2 * TOT / 4, 256, 0, stream>>>(sx, si, xsb,
            iS0, nullptr, nullptr, iF0, nullptr, nullptr,
            nullptr, iS1, nullptr, iF1, 1);
        search_kernel<2><<<2 * TOT / 4, 256, 0, stream>>>(sx, si, xsb,
            iS0, iS1, nullptr, iF0, iF1, nullptr,
            nullptr, iS2, nullptr, iF2, 1);
        search_kernel<3><<<TOT / 4, 256, 0, stream>>>(sx, si, xsb,
            iS0, iS1, iS2, iF0, iF1, iF2,
            nullptr, nullptr, nullptr, iF3, 0);
    } else {
        round_full_kernel<0><<<2048, 256, 0, stream>>>(pkG, pkP,
            nullptr, nullptr, nullptr, nullptr, nullptr, nullptr,
            dS0, iS0, dF0, iF0, 1);
        round_full_kernel<1><<<2048, 256, 0, stream>>>(pkG, pkP,
            iS0, nullptr, nullptr, iF0, nullptr, nullptr,
            nullptr, iS1, nullptr, iF1, 1);
        round_full_kernel<2><<<2048, 256, 0, stream>>>(pkG, pkP,
            iS0, iS1, nullptr, iF0, iF1, nullptr,
            nullptr, iS2, nullptr, iF2, 1);
        round_full_kernel<3><<<1024, 256, 0, stream>>>(pkG, pkP,
            iS0, iS1, iS2, iF0, iF1, iF2,
            nullptr, nullptr, nullptr, iF3, 0);
    }

    normal_kernel<<<16, 256, 0, stream>>>(preds, normals, dS0, dF0,
                                          iF0, iF1, iF2, iF3, partials);
    final_kernel<<<1, 64, 0, stream>>>(partials, out);
}

// Round 14
// 480.031 us; speedup vs baseline: 9.9180x; 1.1065x over previous
//
#include <hip/hip_runtime.h>
#include <hip/hip_bf16.h>
#include <float.h>
#include <stdint.h>

// Problem constants (fixed by setup_inputs): B=4, N=M=4096, D=3.
#define BATCH 4
#define NPTS  4096
#define TOT   (BATCH * NPTS)   // 16384

// ---------------------------------------------------------------------------
// Kernel 1: pack points into float4 {x, y, z, |p|^2}.
// rr is x*x + y*y + z*z left-to-right, matching jnp.sum(x*x, -1).
// ---------------------------------------------------------------------------
__global__ __launch_bounds__(256) void pack_kernel(
    const float* __restrict__ gts, const float* __restrict__ preds,
    float4* __restrict__ pkG, float4* __restrict__ pkP)
{
    int i = blockIdx.x * blockDim.x + threadIdx.x;   // 0 .. 2*TOT-1
    if (i >= 2 * TOT) return;
    const float* src = (i < TOT) ? gts : preds;
    float4* dst      = (i < TOT) ? pkG : pkP;
    int k            = (i < TOT) ? i : i - TOT;
    float x = src[3 * k + 0];
    float y = src[3 * k + 1];
    float z = src[3 * k + 2];
    float rr = __fadd_rn(__fadd_rn(__fmul_rn(x, x), __fmul_rn(y, y)), __fmul_rn(z, z));
    dst[k] = make_float4(x, y, z, rr);
}

// ---------------------------------------------------------------------------
// Kernel 2: per-(side,batch) bitonic sort by x (8 blocks, 1024 threads, LDS).
// 64-bit keys {monotone_bits(x) << 32 | idx} -> total order, deterministic.
// Outputs: sx (sorted float4), si (original batch-local idx), xs (sorted x).
// Layout: [side(2)][batch(4)][4096], side 0 = gts, side 1 = preds.
// (Verified in R11-R13 — unchanged.)
// ---------------------------------------------------------------------------
__global__ __launch_bounds__(1024) void sort_kernel(
    const float4* __restrict__ pkG, const float4* __restrict__ pkP,
    float4* __restrict__ sx, int* __restrict__ si, float* __restrict__ xs)
{
    __shared__ unsigned long long keys[NPTS];   // 32 KB
    int side = blockIdx.x >> 2;
    int b = blockIdx.x & 3;
    const float4* src = (side ? pkP : pkG) + (b << 12);
    for (int t = threadIdx.x; t < NPTS; t += 1024) {
        unsigned u = __float_as_uint(src[t].x);
        u = (u & 0x80000000u) ? ~u : (u | 0x80000000u);   // monotone map
        keys[t] = ((unsigned long long)u << 32) | (unsigned)t;
    }
    __syncthreads();
    for (int k = 2; k <= NPTS; k <<= 1) {
        for (int j = k >> 1; j > 0; j >>= 1) {
            for (int t = threadIdx.x; t < NPTS; t += 1024) {
                int ixj = t ^ j;
                if (ixj > t) {
                    unsigned long long a = keys[t], c = keys[ixj];
                    bool up = (t & k) == 0;
                    if (up ? (a > c) : (a < c)) { keys[t] = c; keys[ixj] = a; }
                }
            }
            __syncthreads();
        }
    }
    int base = (int)blockIdx.x << 12;
    for (int t = threadIdx.x; t < NPTS; t += 1024) {
        int orig = (int)(unsigned)(keys[t] & 0xFFFFFFFFu);
        float4 v = src[orig];
        sx[base + t] = v;
        si[base + t] = orig;
        xs[base + t] = v.x;
    }
}

// ---------------------------------------------------------------------------
// Rounds 0-3: sorted-window argmin, OUTER-PRODUCT shape (brute-force-style).
// One wave owns 4 CONSECUTIVE sorted own points (rows, shared wave-wide in
// registers — their windows overlap ~99%). Lanes stream 64-candidate
// coalesced blocks outward from anchor C (two-ballot lower bound of row 1's
// x). Each lane evaluates its candidate against all 4 rows with the EXACT
// verified formula + lex (d, j) updates into per-lane partials (no cross-lane
// traffic). One __ballot per block: a side stops when EVERY lane's candidate
// is "beyond" for ALL rows, i.e. signed dx > 0 and fl(dx)^2 > best + MARGIN.
// Exactness: dx monotone along sorted x at block granularity, best only
// decreases, dx^2 lower-bounds d_true, |fl(d)-d_true| <= ~4e-5 << MARGIN=1e-3
// -> every skipped candidate provably cannot achieve or tie the minimal
// computed d; evaluating a superset is exact (lex updates are order-free).
// Exclusions (round R): j == e_t OR rev_t[j] == ownIn, t < R, inline.
// All-excluded row: best stays FLT_MAX -> never "beyond" -> full scan ->
// bestj = 0 (= numpy argmin of an all-max row). 4 butterflies per wave total.
// ---------------------------------------------------------------------------
template<int R>
__global__ __launch_bounds__(256) void search_kernel(
    const float4* __restrict__ sx, const int* __restrict__ si,
    const float* __restrict__ xs,
    const int* __restrict__ is0, const int* __restrict__ is1, const int* __restrict__ is2,
    const int* __restrict__ if0, const int* __restrict__ if1, const int* __restrict__ if2,
    float* __restrict__ dS, int* __restrict__ iS,
    float* __restrict__ dF, int* __restrict__ iF,
    int do_rows)
{
    int wid  = blockIdx.x * 4 + (threadIdx.x >> 6);   // row-group id
    int lane = threadIdx.x & 63;
    int gHalf = do_rows ? (TOT / 4) : 0;
    bool isRow = wid < gHalf;            // s2f: own = gts, other = preds
    int g = isRow ? wid : wid - gHalf;   // 0 .. TOT/4-1
    int pBase = g << 2;                  // first own slot (4 | 4096: no straddle)
    int b = pBase >> 12;
    int p0 = pBase & (NPTS - 1);
    int obase = b << 12;

    int ownSide = isRow ? 0 : 1;
    const float4* sOwn = sx + (((ownSide << 2) | b) << 12);
    const int*    iOwn = si + (((ownSide << 2) | b) << 12);
    const float4* sOth = sx + ((((1 - ownSide) << 2) | b) << 12);
    const int*    iOth = si + ((((1 - ownSide) << 2) | b) << 12);
    const float*  xOth = xs + ((((1 - ownSide) << 2) | b) << 12);

    float4 ow[4]; int ownIn[4];
    #pragma unroll
    for (int r = 0; r < 4; ++r) {
        ow[r] = sOwn[p0 + r];            // wave-uniform broadcast loads
        ownIn[r] = iOwn[p0 + r];
    }

    int e0[4], e1[4], e2[4];
    #pragma unroll
    for (int r = 0; r < 4; ++r) { e0[r] = -1; e1[r] = -1; e2[r] = -1; }
    if (R > 0) { const int* f = (isRow ? is0 : if0) + obase;
        #pragma unroll
        for (int r = 0; r < 4; ++r) e0[r] = f[ownIn[r]]; }
    if (R > 1) { const int* f = (isRow ? is1 : if1) + obase;
        #pragma unroll
        for (int r = 0; r < 4; ++r) e1[r] = f[ownIn[r]]; }
    if (R > 2) { const int* f = (isRow ? is2 : if2) + obase;
        #pragma unroll
        for (int r = 0; r < 4; ++r) e2[r] = f[ownIn[r]]; }
    const int* r0 = (R > 0) ? (isRow ? if0 : is0) + obase : nullptr;
    const int* r1 = (R > 1) ? (isRow ? if1 : is1) + obase : nullptr;
    const int* r2 = (R > 2) ? (isRow ? if2 : is2) + obase : nullptr;

    // ---- two-ballot lower bound of row-1's x (verified R13 code)
    float bx = ow[1].x;
    float sv1 = xOth[lane << 6];                       // samples 0,64,...,4032
    unsigned long long m1 = __ballot(sv1 < bx);
    int cnt1 = __popcll(m1);
    int base2 = (cnt1 > 0 ? cnt1 - 1 : 0) << 6;
    float sv2 = xOth[base2 + lane];                    // coalesced
    unsigned long long m2 = __ballot(sv2 < bx);
    int C = base2 + __popcll(m2);                      // lower_bound

    float best[4]; int bidx[4];
    #pragma unroll
    for (int r = 0; r < 4; ++r) { best[r] = FLT_MAX; bidx[r] = 0; }
    const float MARGIN = 1e-3f;

    // ---- RIGHT sweep: coalesced 64-blocks from C upward
    for (int pos = C; pos < NPTS; pos += 64) {
        int myp = pos + lane;
        bool in = myp < NPTS;
        float4 q = in ? sOth[myp] : make_float4(0.f, 0.f, 0.f, 0.f);
        int j   = in ? iOth[myp] : 0;
        int rr0 = (R > 0 && in) ? r0[j] : -2;
        int rr1 = (R > 1 && in) ? r1[j] : -2;
        int rr2 = (R > 2 && in) ? r2[j] : -2;
        bool cont = false;
        if (in) {
            #pragma unroll
            for (int r = 0; r < 4; ++r) {
                float zz = __fadd_rn(__fadd_rn(__fmul_rn(ow[r].x, q.x),
                                               __fmul_rn(ow[r].y, q.y)),
                                     __fmul_rn(ow[r].z, q.z));
                float d = __fmaf_rn(-2.0f, zz, __fadd_rn(ow[r].w, q.w));
                bool ex = false;
                if (R > 0) ex = (j == e0[r]) || (rr0 == ownIn[r]);
                if (R > 1) ex = ex || (j == e1[r]) || (rr1 == ownIn[r]);
                if (R > 2) ex = ex || (j == e2[r]) || (rr2 == ownIn[r]);
                if (!ex && (d < best[r] || (d == best[r] && j < bidx[r]))) {
                    best[r] = d; bidx[r] = j;
                }
                float dxr = __fsub_rn(q.x, ow[r].x);
                bool beyond = (dxr > 0.0f) &&
                              (__fmul_rn(dxr, dxr) > best[r] + MARGIN);
                cont = cont || !beyond;
            }
        }
        if (!__ballot(cont)) break;
    }

    // ---- LEFT sweep: coalesced 64-blocks from C-64 downward
    for (int pos = C - 64; pos > -64; pos -= 64) {
        int myp = pos + lane;
        bool in = myp >= 0;
        float4 q = in ? sOth[myp] : make_float4(0.f, 0.f, 0.f, 0.f);
        int j   = in ? iOth[myp] : 0;
        int rr0 = (R > 0 && in) ? r0[j] : -2;
        int rr1 = (R > 1 && in) ? r1[j] : -2;
        int rr2 = (R > 2 && in) ? r2[j] : -2;
        bool cont = false;
        if (in) {
            #pragma unroll
            for (int r = 0; r < 4; ++r) {
                float zz = __fadd_rn(__fadd_rn(__fmul_rn(ow[r].x, q.x),
                                               __fmul_rn(ow[r].y, q.y)),
                                     __fmul_rn(ow[r].z, q.z));
                float d = __fmaf_rn(-2.0f, zz, __fadd_rn(ow[r].w, q.w));
                bool ex = false;
                if (R > 0) ex = (j == e0[r]) || (rr0 == ownIn[r]);
                if (R > 1) ex = ex || (j == e1[r]) || (rr1 == ownIn[r]);
                if (R > 2) ex = ex || (j == e2[r]) || (rr2 == ownIn[r]);
                if (!ex && (d < best[r] || (d == best[r] && j < bidx[r]))) {
                    best[r] = d; bidx[r] = j;
                }
                float dxr = __fsub_rn(ow[r].x, q.x);
                bool beyond = (dxr > 0.0f) &&
                              (__fmul_rn(dxr, dxr) > best[r] + MARGIN);
                cont = cont || !beyond;
            }
        }
        if (!__ballot(cont)) break;
    }

    // ---- per-row wave lex-min + write (verified butterfly pattern)
    float* dOut = isRow ? dS : dF;
    int*   iOut = isRow ? iS : iF;
    #pragma unroll
    for (int r = 0; r < 4; ++r) {
        float v = best[r]; int ix = bidx[r];
        #pragma unroll
        for (int off = 1; off < 64; off <<= 1) {
            float v2 = __shfl_xor(v, off);
            int   i2 = __shfl_xor(ix, off);
            if (v2 < v || (v2 == v && i2 < ix)) { v = v2; ix = i2; }
        }
        if (lane == 0) {
            iOut[obase + ownIn[r]] = ix;
            if (R == 0) dOut[obase + ownIn[r]] = v;
        }
    }
}

// ---------------------------------------------------------------------------
// Fallback full-rescan kernel (verified in R4) — used only if ws too small.
// ---------------------------------------------------------------------------
template<int R>
__global__ __launch_bounds__(256) void round_full_kernel(
    const float4* __restrict__ pkG, const float4* __restrict__ pkP,
    const int* __restrict__ is0, const int* __restrict__ is1, const int* __restrict__ is2,
    const int* __restrict__ if0, const int* __restrict__ if1, const int* __restrict__ if2,
    float* __restrict__ dS, int* __restrict__ iS,
    float* __restrict__ dF, int* __restrict__ iF,
    int do_rows)
{
    int half    = do_rows ? (gridDim.x >> 1) : gridDim.x;
    bool isRow  = do_rows && ((int)blockIdx.x < half);
    int dirBlk  = isRow ? blockIdx.x : (blockIdx.x - (do_rows ? half : 0));

    const float4* own = isRow ? pkG : pkP;
    const float4* oth = isRow ? pkP : pkG;
    const int* exOwn0 = isRow ? is0 : if0;
    const int* exOwn1 = isRow ? is1 : if1;
    const int* exOwn2 = isRow ? is2 : if2;
    const int* exOth0 = isRow ? if0 : is0;
    const int* exOth1 = isRow ? if1 : is1;
    const int* exOth2 = isRow ? if2 : is2;
    float* dOut = isRow ? dS : dF;
    int*   iOut = isRow ? iS : iF;

    int lane = threadIdx.x & 63;
    int wave = threadIdx.x >> 6;
    int ownBase = dirBlk * 16 + wave * 4;
    int b = ownBase >> 12;
    int obase = b << 12;

    float ox[4], oy[4], oz[4], orr[4];
    int ownIn[4];
    int oe0[4], oe1[4], oe2[4];
    #pragma unroll
    for (int r = 0; r < 4; ++r) {
        float4 p = own[ownBase + r];
        ox[r] = p.x; oy[r] = p.y; oz[r] = p.z; orr[r] = p.w;
        ownIn[r] = (ownBase & (NPTS - 1)) + r;
        oe0[r] = 0; oe1[r] = 0; oe2[r] = 0;
        if (R > 0) oe0[r] = exOwn0[ownBase + r];
        if (R > 1) oe1[r] = exOwn1[ownBase + r];
        if (R > 2) oe2[r] = exOwn2[ownBase + r];
    }

    float best[4]; int bidx[4];
    #pragma unroll
    for (int r = 0; r < 4; ++r) { best[r] = FLT_MAX; bidx[r] = 0; }

    for (int j = lane; j < NPTS; j += 64) {
        float4 q = oth[obase + j];
        int eo0 = 0, eo1 = 0, eo2 = 0;
        if (R > 0) eo0 = exOth0[obase + j];
        if (R > 1) eo1 = exOth1[obase + j];
        if (R > 2) eo2 = exOth2[obase + j];
        #pragma unroll
        for (int r = 0; r < 4; ++r) {
            float zz = __fadd_rn(__fadd_rn(__fmul_rn(ox[r], q.x),
                                           __fmul_rn(oy[r], q.y)),
                                 __fmul_rn(oz[r], q.z));
            float d = __fmaf_rn(-2.0f, zz, __fadd_rn(orr[r], q.w));
            bool ex = false;
            if (R > 0) ex = ex || (j == oe0[r]) || (eo0 == ownIn[r]);
            if (R > 1) ex = ex || (j == oe1[r]) || (eo1 == ownIn[r]);
            if (R > 2) ex = ex || (j == oe2[r]) || (eo2 == ownIn[r]);
            if (ex) d = FLT_MAX;
            if (d < best[r]) { best[r] = d; bidx[r] = j; }
        }
    }

    #pragma unroll
    for (int r = 0; r < 4; ++r) {
        float v = best[r]; int ix = bidx[r];
        #pragma unroll
        for (int off = 32; off > 0; off >>= 1) {
            float v2 = __shfl_xor(v, off);
            int   i2 = __shfl_xor(ix, off);
            if (v2 < v || (v2 == v && i2 < ix)) { v = v2; ix = i2; }
        }
        if (lane == 0) {
            iOut[ownBase + r] = ix;
            if (dOut) dOut[ownBase + r] = v;
        }
    }
}

// ---------------------------------------------------------------------------
// Per-(batch, segment) partial sums (unchanged, verified).
// ---------------------------------------------------------------------------
__global__ __launch_bounds__(256) void normal_kernel(
    const float* __restrict__ preds, const float* __restrict__ normals,
    const float* __restrict__ dS, const float* __restrict__ dF,
    const int* __restrict__ if0, const int* __restrict__ if1,
    const int* __restrict__ if2, const int* __restrict__ if3,
    float4* __restrict__ partials)
{
    int b   = blockIdx.x >> 2;
    int seg = blockIdx.x & 3;
    int t   = threadIdx.x;

    const float* pp = preds + (size_t)b * NPTS * 3;
    float champ = 0.f, s1 = 0.f, s2 = 0.f, s3 = 0.f;

    for (int it = 0; it < 4; ++it) {
        int m  = seg * 1024 + it * 256 + t;
        int gi = b * NPTS + m;
        champ += dF[gi] + dS[gi];

        int i0 = if0[gi];
        float p0x = pp[3 * i0 + 0], p0y = pp[3 * i0 + 1], p0z = pp[3 * i0 + 2];
        float nx = normals[3 * gi + 0], ny = normals[3 * gi + 1], nz = normals[3 * gi + 2];

        int iA = if1[gi];
        s1 += (p0x - pp[3 * iA + 0]) * nx + (p0y - pp[3 * iA + 1]) * ny + (p0z - pp[3 * iA + 2]) * nz;
        int iB = if2[gi];
        s2 += (p0x - pp[3 * iB + 0]) * nx + (p0y - pp[3 * iB + 1]) * ny + (p0z - pp[3 * iB + 2]) * nz;
        int iC = if3[gi];
        s3 += (p0x - pp[3 * iC + 0]) * nx + (p0y - pp[3 * iC + 1]) * ny + (p0z - pp[3 * iC + 2]) * nz;
    }

    #pragma unroll
    for (int off = 32; off > 0; off >>= 1) {
        champ += __shfl_xor(champ, off);
        s1    += __shfl_xor(s1, off);
        s2    += __shfl_xor(s2, off);
        s3    += __shfl_xor(s3, off);
    }
    __shared__ float4 red[4];
    int wave = t >> 6, lane = t & 63;
    if (lane == 0) red[wave] = make_float4(champ, s1, s2, s3);
    __syncthreads();
    if (t == 0) {
        float4 a = red[0];
        for (int w = 1; w < 4; ++w) {
            a.x += red[w].x; a.y += red[w].y; a.z += red[w].z; a.w += red[w].w;
        }
        partials[blockIdx.x] = a;
    }
}

__global__ void final_kernel(const float4* __restrict__ partials, float* __restrict__ out)
{
    if (blockIdx.x == 0 && threadIdx.x == 0) {
        float champ = 0.f;
        float s[BATCH][3];
        for (int b = 0; b < BATCH; ++b) for (int k = 0; k < 3; ++k) s[b][k] = 0.f;
        for (int blk = 0; blk < 16; ++blk) {
            float4 p = partials[blk];
            int b = blk >> 2;
            champ   += p.x;
            s[b][0] += p.y;
            s[b][1] += p.z;
            s[b][2] += p.w;
        }
        float nl = 0.f;
        for (int k = 0; k < 3; ++k)
            for (int b = 0; b < BATCH; ++b)
                nl += fabsf(s[b][k]);
        out[0] = 1.0f + champ + 10.0f * nl;
    }
}

// ---------------------------------------------------------------------------
// Launch. Workspace (~1.9 MB):
//   pkG | pkP (256 KB ea) | sx (512 KB) | si (128 KB) | xs (128 KB) |
//   iS0..iS2, iF0..iF3 (7 x 64 KB) | dS0 | dF0 | partials
// Fallback: verified full-rescan chain if ws too small.
// ---------------------------------------------------------------------------
extern "C" void kernel_launch(void* const* d_in, const int* in_sizes, int n_in,
                              void* d_out, int out_size, void* d_ws, size_t ws_size,
                              hipStream_t stream) {
    const float* gts     = (const float*)d_in[0];
    const float* preds   = (const float*)d_in[1];
    const float* normals = (const float*)d_in[2];
    float* out = (float*)d_out;

    char* ws = (char*)d_ws;
    float4* pkG = (float4*)ws;
    float4* pkP = (float4*)(ws + 262144);
    float4* sx  = (float4*)(ws + 524288);
    int*    si  = (int*)(ws + 1048576);
    float*  xsb = (float*)(ws + 1179648);
    int* iS0 = (int*)(ws + 1310720);
    int* iS1 = iS0 + TOT;
    int* iS2 = iS1 + TOT;
    int* iF0 = iS2 + TOT;
    int* iF1 = iF0 + TOT;
    int* iF2 = iF1 + TOT;
    int* iF3 = iF2 + TOT;
    float* dS0 = (float*)(iF3 + TOT);
    float* dF0 = dS0 + TOT;
    float4* partials = (float4*)(dF0 + TOT);
    size_t need = 1310720 + (size_t)9 * 65536 + 256;   // ~1.9 MB

    pack_kernel<<<(2 * TOT + 255) / 256, 256, 0, stream>>>(gts, preds, pkG, pkP);

    if (ws_size >= need) {
        sort_kernel<<<8, 1024, 0, stream>>>(pkG, pkP, sx, si, xsb);

        // 4 rows per wave, 4 waves per block:
        // rounds 0-2: 2*TOT/4 row-groups / 4 = 2048 blocks; round 3: 1024.
        search_kernel<0><<<2048, 256, 0, stream>>>(sx, si, xsb,
            nullptr, nullptr, nullptr, nullptr, nullptr, nullptr,
            dS0, iS0, dF0, iF0, 1);
        search_kernel<1><<<2048, 256, 0, stream>>>(sx, si, xsb,
            iS0, nullptr, nullptr, iF0, nullptr, nullptr,
            nullptr, iS1, nullptr, iF1, 1);
        search_kernel<2><<<2048, 256, 0, stream>>>(sx, si, xsb,
            iS0, iS1, nullptr, iF0, iF1, nullptr,
            nullptr, iS2, nullptr, iF2, 1);
        search_kernel<3><<<1024, 256, 0, stream>>>(sx, si, xsb,
            iS0, iS1, iS2, iF0, iF1, iF2,
            nullptr, nullptr, nullptr, iF3, 0);
    } else {
        round_full_kernel<0><<<2048, 256, 0, stream>>>(pkG, pkP,
            nullptr, nullptr, nullptr, nullptr, nullptr, nullptr,
            dS0, iS0, dF0, iF0, 1);
        round_full_kernel<1><<<2048, 256, 0, stream>>>(pkG, pkP,
            iS0, nullptr, nullptr, iF0, nullptr, nullptr,
            nullptr, iS1, nullptr, iF1, 1);
        round_full_kernel<2><<<2048, 256, 0, stream>>>(pkG, pkP,
            iS0, iS1, nullptr, iF0, iF1, nullptr,
            nullptr, iS2, nullptr, iF2, 1);
        round_full_kernel<3><<<1024, 256, 0, stream>>>(pkG, pkP,
            iS0, iS1, iS2, iF0, iF1, iF2,
            nullptr, nullptr, nullptr, iF3, 0);
    }

    normal_kernel<<<16, 256, 0, stream>>>(preds, normals, dS0, dF0,
                                          iF0, iF1, iF2, iF3, partials);
    final_kernel<<<1, 64, 0, stream>>>(partials, out);
}

// Round 15
// 118.663 us; speedup vs baseline: 40.1218x; 4.0453x over previous
//
#include <hip/hip_runtime.h>
#include <hip/hip_bf16.h>
#include <float.h>
#include <stdint.h>

// Problem constants (fixed by setup_inputs): B=4, N=M=4096, D=3.
#define BATCH 4
#define NPTS  4096
#define TOT   (BATCH * NPTS)   // 16384

typedef float v2f __attribute__((ext_vector_type(2)));
typedef float v4f __attribute__((ext_vector_type(4)));

// Stripe scheme: stripe s = {j : j % NS == s}, M = NPTS/NS members each.
template<int NS>
__device__ __forceinline__ int tslot(int n) {
    constexpr int M = NPTS / NS;
    return (n & (NS - 1)) * M + (n / NS);
}

// ---------------------------------------------------------------------------
// Kernel 1: pack points into float4 {x, y, z, |p|^2} + stripe-major transposed
// copy + (optional) pair-SoA copy for the packed round0.
// rr is x*x + y*y + z*z left-to-right, matching jnp.sum(x*x, -1).
// ---------------------------------------------------------------------------
template<int NS>
__global__ __launch_bounds__(256) void pack_kernel(
    const float* __restrict__ gts, const float* __restrict__ preds,
    float4* __restrict__ pkG, float4* __restrict__ pkP,
    float4* __restrict__ pkGT, float4* __restrict__ pkPT,
    float* __restrict__ pairG, float* __restrict__ pairP)
{
    int i = blockIdx.x * blockDim.x + threadIdx.x;   // 0 .. 2*TOT-1
    if (i >= 2 * TOT) return;
    const float* src = (i < TOT) ? gts : preds;
    float4* dst      = (i < TOT) ? pkG : pkP;
    float4* dstT     = (i < TOT) ? pkGT : pkPT;
    float* pairDst   = (i < TOT) ? pairG : pairP;
    int k            = (i < TOT) ? i : i - TOT;
    float x = src[3 * k + 0];
    float y = src[3 * k + 1];
    float z = src[3 * k + 2];
    float rr = __fadd_rn(__fadd_rn(__fmul_rn(x, x), __fmul_rn(y, y)), __fmul_rn(z, z));
    float4 v = make_float4(x, y, z, rr);
    dst[k] = v;
    int b = k >> 12, n = k & (NPTS - 1);
    dstT[(b << 12) + tslot<NS>(n)] = v;
    if (pairDst) {
        int u = n >> 7, l = n & 63, hb = (n >> 6) & 1;
        size_t fb = ((size_t)(b * 2048 + (u << 6) + l)) * 8 + hb;
        pairDst[fb + 0] = x;
        pairDst[fb + 2] = y;
        pairDst[fb + 4] = z;
        pairDst[fb + 6] = rr;
    }
}

// ---------------------------------------------------------------------------
// Round 0, PACKED fp32, ILP version: each v_pk_* op is its own asm statement
// with SSA operands, so the scheduler interleaves the 4 independent r-chains
// and hoists loads. Ops, order, and rounding are IDENTICAL to the verified
// scalar sequence per half: zz = ((ox*x)+(oy*y))+(oz*z); s = orr+w;
// d = fma(-2,zz,s). Per-lane order jA then jB, u ascending = j ascending, so
// strict '<' tie-breaking matches numpy argmin.
// Lane l IS stripe l (NS=64): per-lane minima are the stripe partials.
// (Verified: R10, 118.19 us wall, absmax 64.)
// ---------------------------------------------------------------------------
__global__ __launch_bounds__(256) void round0_packed(
    const float4* __restrict__ pkG, const float4* __restrict__ pkP,
    const float* __restrict__ pairG, const float* __restrict__ pairP,
    float* __restrict__ dS, int* __restrict__ iS,
    float* __restrict__ dF, int* __restrict__ iF,
    int* __restrict__ iST, int* __restrict__ iFT,
    int2* __restrict__ stripes)   // [2][TOT][64]
{
    int wid  = blockIdx.x * 4 + (threadIdx.x >> 6);   // 0..8191
    int lane = threadIdx.x & 63;
    bool isRow = wid < 4096;
    int w = isRow ? wid : wid - 4096;
    int ownBase = w * 4;                 // 4 | 4096 -> no batch straddle
    int b = ownBase >> 12;
    int obase = b << 12;

    const float4* own = isRow ? pkG : pkP;
    const float* pair = isRow ? pairP : pairG;
    float* dOut = isRow ? dS : dF;
    int*   iOut = isRow ? iS : iF;
    int*   iOutT = isRow ? iST : iFT;
    int dirOfs  = isRow ? 0 : TOT;

    v2f ox2[4], oy2[4], oz2[4], ow2[4];
    #pragma unroll
    for (int r = 0; r < 4; ++r) {
        float4 p = own[ownBase + r];
        ox2[r] = (v2f){p.x, p.x};
        oy2[r] = (v2f){p.y, p.y};
        oz2[r] = (v2f){p.z, p.z};
        ow2[r] = (v2f){p.w, p.w};
    }
    v2f n2 = (v2f){-2.0f, -2.0f};

    float best[4]; int bidx[4];
    #pragma unroll
    for (int r = 0; r < 4; ++r) { best[r] = FLT_MAX; bidx[r] = 0; }

    const v4f* pb = (const v4f*)pair + obase;   // batch b at v4f index obase
    #pragma unroll 2
    for (int u = 0; u < 32; ++u) {
        int pi = (((u << 6) + lane) << 1);
        v4f h0 = pb[pi];
        v4f h1 = pb[pi + 1];
        v2f xab = h0.xy, yab = h0.zw, zab = h1.xy, wab = h1.zw;
        int jA = lane + (u << 7), jB = jA + 64;
        #pragma unroll
        for (int r = 0; r < 4; ++r) {
            v2f t0, t1, t2, s, dd;
            asm("v_pk_mul_f32 %0, %1, %2" : "=v"(t0) : "v"(ox2[r]), "v"(xab));
            asm("v_pk_mul_f32 %0, %1, %2" : "=v"(t1) : "v"(oy2[r]), "v"(yab));
            asm("v_pk_mul_f32 %0, %1, %2" : "=v"(t2) : "v"(oz2[r]), "v"(zab));
            asm("v_pk_add_f32 %0, %1, %2" : "=v"(s)  : "v"(ow2[r]), "v"(wab));
            asm("v_pk_add_f32 %0, %1, %2" : "=v"(t0) : "v"(t0), "v"(t1));
            asm("v_pk_add_f32 %0, %1, %2" : "=v"(t0) : "v"(t0), "v"(t2));
            asm("v_pk_fma_f32 %0, %1, %2, %3" : "=v"(dd) : "v"(n2), "v"(t0), "v"(s));
            float dA = dd.x, dB = dd.y;
            if (dA < best[r]) { best[r] = dA; bidx[r] = jA; }
            if (dB < best[r]) { best[r] = dB; bidx[r] = jB; }
        }
    }

    #pragma unroll
    for (int r = 0; r < 4; ++r) {
        float v = best[r]; int ix = bidx[r];
        stripes[(size_t)(dirOfs + ownBase + r) * 64 + lane] =
            make_int2(__float_as_int(v), ix);
        #pragma unroll
        for (int off = 1; off <= 32; off <<= 1) {
            float v2 = __shfl_xor(v, off);
            int   i2 = __shfl_xor(ix, off);
            if (v2 < v || (v2 == v && i2 < ix)) { v = v2; ix = i2; }
        }
        if (lane == 0) {
            iOut[ownBase + r] = ix;
            dOut[ownBase + r] = v;
            int nl = (ownBase & (NPTS - 1)) + r;
            iOutT[obase + tslot<64>(nl)] = ix;
        }
    }
}

// ---------------------------------------------------------------------------
// Round 0, scalar (verified) — NS=16 tier.
// ---------------------------------------------------------------------------
template<int NS>
__global__ __launch_bounds__(256) void round0_kernel(
    const float4* __restrict__ pkG, const float4* __restrict__ pkP,
    float* __restrict__ dS, int* __restrict__ iS,
    float* __restrict__ dF, int* __restrict__ iF,
    int* __restrict__ iST, int* __restrict__ iFT,
    int2* __restrict__ stripes)
{
    int wid  = blockIdx.x * 4 + (threadIdx.x >> 6);
    int lane = threadIdx.x & 63;
    bool isRow = wid < 4096;
    int w = isRow ? wid : wid - 4096;
    int ownBase = w * 4;
    int b = ownBase >> 12;
    int obase = b << 12;

    const float4* own = isRow ? pkG : pkP;
    const float4* oth = isRow ? pkP : pkG;
    float* dOut = isRow ? dS : dF;
    int*   iOut = isRow ? iS : iF;
    int*   iOutT = isRow ? iST : iFT;
    int dirOfs  = isRow ? 0 : TOT;

    float ox[4], oy[4], oz[4], orr[4];
    #pragma unroll
    for (int r = 0; r < 4; ++r) {
        float4 p = own[ownBase + r];
        ox[r] = p.x; oy[r] = p.y; oz[r] = p.z; orr[r] = p.w;
    }
    float best[4]; int bidx[4];
    #pragma unroll
    for (int r = 0; r < 4; ++r) { best[r] = FLT_MAX; bidx[r] = 0; }

    const float4* qp = oth + obase + lane;
    #pragma unroll 2
    for (int t = 0; t < 64; ++t) {
        float4 q = qp[t * 64];
        int j = lane + (t << 6);
        #pragma unroll
        for (int r = 0; r < 4; ++r) {
            float zz = __fadd_rn(__fadd_rn(__fmul_rn(ox[r], q.x),
                                           __fmul_rn(oy[r], q.y)),
                                 __fmul_rn(oz[r], q.z));
            float d = __fmaf_rn(-2.0f, zz, __fadd_rn(orr[r], q.w));
            if (d < best[r]) { best[r] = d; bidx[r] = j; }
        }
    }

    #pragma unroll
    for (int r = 0; r < 4; ++r) {
        float v = best[r]; int ix = bidx[r];
        #pragma unroll
        for (int off = NS; off <= 32; off <<= 1) {
            float v2 = __shfl_xor(v, off);
            int   i2 = __shfl_xor(ix, off);
            if (v2 < v || (v2 == v && i2 < ix)) { v = v2; ix = i2; }
        }
        if (lane < NS)
            stripes[(size_t)(dirOfs + ownBase + r) * NS + lane] =
                make_int2(__float_as_int(v), ix);
        #pragma unroll
        for (int off = 1; off < NS; off <<= 1) {
            float v2 = __shfl_xor(v, off);
            int   i2 = __shfl_xor(ix, off);
            if (v2 < v || (v2 == v && i2 < ix)) { v = v2; ix = i2; }
        }
        if (lane == 0) {
            iOut[ownBase + r] = ix;
            dOut[ownBase + r] = v;
            int nl = (ownBase & (NPTS - 1)) + r;
            iOutT[obase + tslot<NS>(nl)] = ix;
        }
    }
}

// ---------------------------------------------------------------------------
// Rounds 1-3, incremental stripe invalidation with WRITE-BACK.
// BATCHED: 4 own points per wave (16 per block) — 4 independent latency
// chains per wave to hide the cold stripe-key / rescan loads, and 4x fewer
// blocks re-staging the 16 KB exTab. Logic per point is unchanged and
// bit-identical: check each stripe winner against ONLY the newest exclusions
// (invariant: stored stripe entries are exact under E_{R-1}); rescan invalid
// stripes under the full cumulative set; write back.
// ---------------------------------------------------------------------------
template<int R, int NS>
__global__ __launch_bounds__(256) void roundR_kernel(
    const float4* __restrict__ pkG, const float4* __restrict__ pkP,
    const float4* __restrict__ pkGT, const float4* __restrict__ pkPT,
    int2* __restrict__ stripes,
    const int* __restrict__ is0, const int* __restrict__ is1, const int* __restrict__ is2,
    const int* __restrict__ if0, const int* __restrict__ if1, const int* __restrict__ if2,
    const int* __restrict__ is0T, const int* __restrict__ is1T, const int* __restrict__ is2T,
    const int* __restrict__ if0T, const int* __restrict__ if1T, const int* __restrict__ if2T,
    int* __restrict__ iS, int* __restrict__ iF,
    int* __restrict__ iST, int* __restrict__ iFT,
    int do_rows)
{
    constexpr int M = NPTS / NS;      // members per stripe
    constexpr int ITERS = M / 64;     // 64-lane passes per rescan

    __shared__ int exTab[NPTS];       // 16 KB staged newest reverse table

    int lane = threadIdx.x & 63;
    int wave = threadIdx.x >> 6;
    int slot0 = (blockIdx.x * 4 + wave) * 4;   // first own-slot of this wave
    int half = do_rows ? TOT : 0;
    bool isRow = slot0 < half;                 // uniform over the 4 slots
    int i0 = isRow ? slot0 : slot0 - half;     // first own index

    // ---- block-uniform staging (block spans 16 slots: one dir, one batch)
    {
        int bSlot0 = blockIdx.x * 16;
        bool blkRow = do_rows && (bSlot0 < half);
        int iFirst = blkRow ? bSlot0 : bSlot0 - half;
        int stObase = iFirst & ~(NPTS - 1);
        const int* stSrc = (blkRow ? (R == 1 ? if0 : R == 2 ? if1 : if2)
                                   : (R == 1 ? is0 : R == 2 ? is1 : is2)) + stObase;
        const int4* s4 = (const int4*)stSrc;
        int4* t4 = (int4*)exTab;
        #pragma unroll
        for (int k = 0; k < NPTS / 4 / 256; ++k)
            t4[k * 256 + threadIdx.x] = s4[k * 256 + threadIdx.x];
        __syncthreads();
    }

    const float4* ownp = isRow ? pkG : pkP;
    const float4* othT = isRow ? pkPT : pkGT;
    const int* exOwn0 = isRow ? is0 : if0;
    const int* exOwn1 = isRow ? is1 : if1;
    const int* exOwn2 = isRow ? is2 : if2;
    const int* x0 = isRow ? if0T : is0T;     // transposed cumulative reverse
    const int* x1 = isRow ? if1T : is1T;
    const int* x2 = isRow ? if2T : is2T;
    int* iOut  = isRow ? iS : iF;
    int* iOutT = isRow ? iST : iFT;
    int dirOfs = isRow ? 0 : TOT;

    int b = i0 >> 12;
    int obase = b << 12;
    const float4* tp = othT + obase;
    const int* x0b = x0 + obase;
    const int* x1b = x1 + obase;
    const int* x2b = x2 + obase;

    #pragma unroll 1
    for (int p = 0; p < 4; ++p) {
        int i = i0 + p;
        int ownIn = i & (NPTS - 1);

        int e0 = exOwn0[i];
        int e1 = (R > 1) ? exOwn1[i] : -1;
        int e2 = (R > 2) ? exOwn2[i] : -1;
        int eNew = (R == 1) ? e0 : (R == 2) ? e1 : e2;

        int2* myStripes = stripes + (size_t)(dirOfs + i) * NS;

        bool excl = false;
        int2 key = make_int2(0x7F7FFFFF, 0x7FFFFFFF);
        if (lane < NS) {
            key = myStripes[lane];
            int jw = key.y;
            if (jw < NPTS)   // sentinel (all-excluded stripe) never wins/changes
                excl = (jw == eNew) || (exTab[jw] == ownIn);
        }
        unsigned long long mask = __ballot(excl);

        float kd = (lane < NS && !excl) ? __int_as_float(key.x) : FLT_MAX;
        int   kj = (lane < NS && !excl) ? key.y : 0x7FFFFFFF;

        if (mask) {
            float4 pq = ownp[i];
            while (mask) {
                int s = __ffsll(mask) - 1;          // wave-uniform stripe id
                mask &= mask - 1;
                int sb = s * M;
                float rd = FLT_MAX; int rj = 0x7FFFFFFF;
                #pragma unroll
                for (int it = 0; it < ITERS; ++it) {
                    int k = (it << 6) + lane;        // 0..M-1, coalesced
                    int j = s + k * NS;              // original other-index
                    float4 q = tp[sb + k];
                    float zz = __fadd_rn(__fadd_rn(__fmul_rn(pq.x, q.x),
                                                   __fmul_rn(pq.y, q.y)),
                                         __fmul_rn(pq.z, q.z));
                    float d = __fmaf_rn(-2.0f, zz, __fadd_rn(pq.w, q.w));
                    bool ex = (j == e0) || (x0b[sb + k] == ownIn);
                    if (R > 1) ex = ex || (j == e1) || (x1b[sb + k] == ownIn);
                    if (R > 2) ex = ex || (j == e2) || (x2b[sb + k] == ownIn);
                    if (!ex && (d < rd || (d == rd && j < rj))) { rd = d; rj = j; }
                }
                #pragma unroll
                for (int off = 1; off < 64; off <<= 1) {
                    float v2 = __shfl_xor(rd, off);
                    int   i2 = __shfl_xor(rj, off);
                    if (v2 < rd || (v2 == rd && i2 < rj)) { rd = v2; rj = i2; }
                }
                if (lane == s) {
                    kd = rd; kj = rj;
                    myStripes[s] = make_int2(__float_as_int(rd), rj);  // write-back
                }
            }
        }

        #pragma unroll
        for (int off = 1; off < 64; off <<= 1) {
            float v2 = __shfl_xor(kd, off);
            int   i2 = __shfl_xor(kj, off);
            if (v2 < kd || (v2 == kd && i2 < kj)) { kd = v2; kj = i2; }
        }
        if (lane == 0) {
            iOut[i] = kj;
            if (iOutT) iOutT[obase + tslot<NS>(ownIn)] = kj;
        }
    }
}

// ---------------------------------------------------------------------------
// Fallback full-rescan kernel (verified) — used only if ws_size is too small.
// ---------------------------------------------------------------------------
template<int R>
__global__ __launch_bounds__(256) void round_full_kernel(
    const float4* __restrict__ pkG, const float4* __restrict__ pkP,
    const int* __restrict__ is0, const int* __restrict__ is1, const int* __restrict__ is2,
    const int* __restrict__ if0, const int* __restrict__ if1, const int* __restrict__ if2,
    float* __restrict__ dS, int* __restrict__ iS,
    float* __restrict__ dF, int* __restrict__ iF,
    int do_rows)
{
    int half    = do_rows ? (gridDim.x >> 1) : gridDim.x;
    bool isRow  = do_rows && ((int)blockIdx.x < half);
    int dirBlk  = isRow ? blockIdx.x : (blockIdx.x - (do_rows ? half : 0));

    const float4* own = isRow ? pkG : pkP;
    const float4* oth = isRow ? pkP : pkG;
    const int* exOwn0 = isRow ? is0 : if0;
    const int* exOwn1 = isRow ? is1 : if1;
    const int* exOwn2 = isRow ? is2 : if2;
    const int* exOth0 = isRow ? if0 : is0;
    const int* exOth1 = isRow ? if1 : is1;
    const int* exOth2 = isRow ? if2 : is2;
    float* dOut = isRow ? dS : dF;
    int*   iOut = isRow ? iS : iF;

    int lane = threadIdx.x & 63;
    int wave = threadIdx.x >> 6;
    int ownBase = dirBlk * 16 + wave * 4;
    int b = ownBase >> 12;
    int obase = b << 12;

    float ox[4], oy[4], oz[4], orr[4];
    int ownIn[4];
    int oe0[4], oe1[4], oe2[4];
    #pragma unroll
    for (int r = 0; r < 4; ++r) {
        float4 p = own[ownBase + r];
        ox[r] = p.x; oy[r] = p.y; oz[r] = p.z; orr[r] = p.w;
        ownIn[r] = (ownBase & (NPTS - 1)) + r;
        oe0[r] = 0; oe1[r] = 0; oe2[r] = 0;
        if (R > 0) oe0[r] = exOwn0[ownBase + r];
        if (R > 1) oe1[r] = exOwn1[ownBase + r];
        if (R > 2) oe2[r] = exOwn2[ownBase + r];
    }

    float best[4]; int bidx[4];
    #pragma unroll
    for (int r = 0; r < 4; ++r) { best[r] = FLT_MAX; bidx[r] = 0; }

    for (int j = lane; j < NPTS; j += 64) {
        float4 q = oth[obase + j];
        int eo0 = 0, eo1 = 0, eo2 = 0;
        if (R > 0) eo0 = exOth0[obase + j];
        if (R > 1) eo1 = exOth1[obase + j];
        if (R > 2) eo2 = exOth2[obase + j];
        #pragma unroll
        for (int r = 0; r < 4; ++r) {
            float zz = __fadd_rn(__fadd_rn(__fmul_rn(ox[r], q.x),
                                           __fmul_rn(oy[r], q.y)),
                                 __fmul_rn(oz[r], q.z));
            float d = __fmaf_rn(-2.0f, zz, __fadd_rn(orr[r], q.w));
            bool ex = false;
            if (R > 0) ex = ex || (j == oe0[r]) || (eo0 == ownIn[r]);
            if (R > 1) ex = ex || (j == oe1[r]) || (eo1 == ownIn[r]);
            if (R > 2) ex = ex || (j == oe2[r]) || (eo2 == ownIn[r]);
            if (ex) d = FLT_MAX;
            if (d < best[r]) { best[r] = d; bidx[r] = j; }
        }
    }

    #pragma unroll
    for (int r = 0; r < 4; ++r) {
        float v = best[r]; int ix = bidx[r];
        #pragma unroll
        for (int off = 32; off > 0; off >>= 1) {
            float v2 = __shfl_xor(v, off);
            int   i2 = __shfl_xor(ix, off);
            if (v2 < v || (v2 == v && i2 < ix)) { v = v2; ix = i2; }
        }
        if (lane == 0) {
            iOut[ownBase + r] = ix;
            if (dOut) dOut[ownBase + r] = v;
        }
    }
}

// ---------------------------------------------------------------------------
// Per-(batch, segment) partial sums (unchanged, verified).
// ---------------------------------------------------------------------------
__global__ __launch_bounds__(256) void normal_kernel(
    const float* __restrict__ preds, const float* __restrict__ normals,
    const float* __restrict__ dS, const float* __restrict__ dF,
    const int* __restrict__ if0, const int* __restrict__ if1,
    const int* __restrict__ if2, const int* __restrict__ if3,
    float4* __restrict__ partials)
{
    int b   = blockIdx.x >> 2;
    int seg = blockIdx.x & 3;
    int t   = threadIdx.x;

    const float* pp = preds + (size_t)b * NPTS * 3;
    float champ = 0.f, s1 = 0.f, s2 = 0.f, s3 = 0.f;

    for (int it = 0; it < 4; ++it) {
        int m  = seg * 1024 + it * 256 + t;
        int gi = b * NPTS + m;
        champ += dF[gi] + dS[gi];

        int i0 = if0[gi];
        float p0x = pp[3 * i0 + 0], p0y = pp[3 * i0 + 1], p0z = pp[3 * i0 + 2];
        float nx = normals[3 * gi + 0], ny = normals[3 * gi + 1], nz = normals[3 * gi + 2];

        int iA = if1[gi];
        s1 += (p0x - pp[3 * iA + 0]) * nx + (p0y - pp[3 * iA + 1]) * ny + (p0z - pp[3 * iA + 2]) * nz;
        int iB = if2[gi];
        s2 += (p0x - pp[3 * iB + 0]) * nx + (p0y - pp[3 * iB + 1]) * ny + (p0z - pp[3 * iB + 2]) * nz;
        int iC = if3[gi];
        s3 += (p0x - pp[3 * iC + 0]) * nx + (p0y - pp[3 * iC + 1]) * ny + (p0z - pp[3 * iC + 2]) * nz;
    }

    #pragma unroll
    for (int off = 32; off > 0; off >>= 1) {
        champ += __shfl_xor(champ, off);
        s1    += __shfl_xor(s1, off);
        s2    += __shfl_xor(s2, off);
        s3    += __shfl_xor(s3, off);
    }
    __shared__ float4 red[4];
    int wave = t >> 6, lane = t & 63;
    if (lane == 0) red[wave] = make_float4(champ, s1, s2, s3);
    __syncthreads();
    if (t == 0) {
        float4 a = red[0];
        for (int w = 1; w < 4; ++w) {
            a.x += red[w].x; a.y += red[w].y; a.z += red[w].z; a.w += red[w].w;
        }
        partials[blockIdx.x] = a;
    }
}

__global__ void final_kernel(const float4* __restrict__ partials, float* __restrict__ out)
{
    if (blockIdx.x == 0 && threadIdx.x == 0) {
        float champ = 0.f;
        float s[BATCH][3];
        for (int b = 0; b < BATCH; ++b) for (int k = 0; k < 3; ++k) s[b][k] = 0.f;
        for (int blk = 0; blk < 16; ++blk) {
            float4 p = partials[blk];
            int b = blk >> 2;
            champ   += p.x;
            s[b][0] += p.y;
            s[b][1] += p.z;
            s[b][2] += p.w;
        }
        float nl = 0.f;
        for (int k = 0; k < 3; ++k)
            for (int b = 0; b < BATCH; ++b)
                nl += fabsf(s[b][k]);
        out[0] = 1.0f + champ + 10.0f * nl;
    }
}

// ---------------------------------------------------------------------------
// Launch. Tiered by ws_size:
//   NS=64 + pairSoA (~19.9 MB): packed round0, batched roundR  <- expected
//   NS=16 (~6.0 MB): scalar round0, batched roundR
//   else: verified full-rescan chain
// ---------------------------------------------------------------------------
extern "C" void kernel_launch(void* const* d_in, const int* in_sizes, int n_in,
                              void* d_out, int out_size, void* d_ws, size_t ws_size,
                              hipStream_t stream) {
    const float* gts     = (const float*)d_in[0];
    const float* preds   = (const float*)d_in[1];
    const float* normals = (const float*)d_in[2];
    float* out = (float*)d_out;

    char* ws = (char*)d_ws;
    float4* pkG  = (float4*)ws;
    float4* pkP  = (float4*)(ws + 262144);
    float4* pkGT = (float4*)(ws + 524288);
    float4* pkPT = (float4*)(ws + 786432);
    int* iS0 = (int*)(ws + 1048576);
    int* iS1 = iS0 + TOT;
    int* iS2 = iS1 + TOT;
    int* iF0 = iS2 + TOT;
    int* iF1 = iF0 + TOT;
    int* iF2 = iF1 + TOT;
    int* iF3 = iF2 + TOT;
    float* dS0 = (float*)(iF3 + TOT);
    float* dF0 = dS0 + TOT;
    float4* partials = (float4*)(dF0 + TOT);
    int* iS0T = (int*)((char*)partials + 256);
    int* iS1T = iS0T + TOT;
    int* iS2T = iS1T + TOT;
    int* iF0T = iS2T + TOT;
    int* iF1T = iF0T + TOT;
    int* iF2T = iF1T + TOT;
    size_t stripeOfs = (size_t)((char*)(iF2T + TOT) - ws);  // ~2.03 MB, aligned
    int2* stripes = (int2*)(ws + stripeOfs);
    size_t pairOfs = stripeOfs + (size_t)2 * TOT * 64 * sizeof(int2);
    float* pairG = (float*)(ws + pairOfs);
    float* pairP = pairG + (size_t)TOT * 8;
    size_t need64 = pairOfs + (size_t)2 * TOT * 8 * sizeof(float);       // ~19.9 MB
    size_t need16 = stripeOfs + (size_t)2 * TOT * 16 * sizeof(int2);     // ~6.0 MB

    if (ws_size >= need64) {
        pack_kernel<64><<<(2 * TOT + 255) / 256, 256, 0, stream>>>(
            gts, preds, pkG, pkP, pkGT, pkPT, pairG, pairP);
        round0_packed<<<2048, 256, 0, stream>>>(pkG, pkP, pairG, pairP,
            dS0, iS0, dF0, iF0, iS0T, iF0T, stripes);
        // batched roundR: 16 own-slots per block
        roundR_kernel<1, 64><<<2048, 256, 0, stream>>>(pkG, pkP, pkGT, pkPT, stripes,
            iS0, iS1, iS2, iF0, iF1, iF2,
            iS0T, iS1T, iS2T, iF0T, iF1T, iF2T,
            iS1, iF1, iS1T, iF1T, 1);
        roundR_kernel<2, 64><<<2048, 256, 0, stream>>>(pkG, pkP, pkGT, pkPT, stripes,
            iS0, iS1, iS2, iF0, iF1, iF2,
            iS0T, iS1T, iS2T, iF0T, iF1T, iF2T,
            iS2, iF2, iS2T, iF2T, 1);
        roundR_kernel<3, 64><<<1024, 256, 0, stream>>>(pkG, pkP, pkGT, pkPT, stripes,
            iS0, iS1, iS2, iF0, iF1, iF2,
            iS0T, iS1T, iS2T, iF0T, iF1T, iF2T,
            nullptr, iF3, nullptr, nullptr, 0);
    } else if (ws_size >= need16) {
        pack_kernel<16><<<(2 * TOT + 255) / 256, 256, 0, stream>>>(
            gts, preds, pkG, pkP, pkGT, pkPT, nullptr, nullptr);
        round0_kernel<16><<<2048, 256, 0, stream>>>(pkG, pkP, dS0, iS0, dF0, iF0,
                                                    iS0T, iF0T, stripes);
        roundR_kernel<1, 16><<<2048, 256, 0, stream>>>(pkG, pkP, pkGT, pkPT, stripes,
            iS0, iS1, iS2, iF0, iF1, iF2,
            iS0T, iS1T, iS2T, iF0T, iF1T, iF2T,
            iS1, iF1, iS1T, iF1T, 1);
        roundR_kernel<2, 16><<<2048, 256, 0, stream>>>(pkG, pkP, pkGT, pkPT, stripes,
            iS0, iS1, iS2, iF0, iF1, iF2,
            iS0T, iS1T, iS2T, iF0T, iF1T, iF2T,
            iS2, iF2, iS2T, iF2T, 1);
        roundR_kernel<3, 16><<<1024, 256, 0, stream>>>(pkG, pkP, pkGT, pkPT, stripes,
            iS0, iS1, iS2, iF0, iF1, iF2,
            iS0T, iS1T, iS2T, iF0T, iF1T, iF2T,
            nullptr, iF3, nullptr, nullptr, 0);
    } else {
        pack_kernel<64><<<(2 * TOT + 255) / 256, 256, 0, stream>>>(
            gts, preds, pkG, pkP, pkGT, pkPT, nullptr, nullptr);
        round_full_kernel<0><<<2048, 256, 0, stream>>>(pkG, pkP,
            nullptr, nullptr, nullptr, nullptr, nullptr, nullptr,
            dS0, iS0, dF0, iF0, 1);
        round_full_kernel<1><<<2048, 256, 0, stream>>>(pkG, pkP,
            iS0, nullptr, nullptr, iF0, nullptr, nullptr,
            nullptr, iS1, nullptr, iF1, 1);
        round_full_kernel<2><<<2048, 256, 0, stream>>>(pkG, pkP,
            iS0, iS1, nullptr, iF0, iF1, nullptr,
            nullptr, iS2, nullptr, iF2, 1);
        round_full_kernel<3><<<1024, 256, 0, stream>>>(pkG, pkP,
            iS0, iS1, iS2, iF0, iF1, iF2,
            nullptr, nullptr, nullptr, iF3, 0);
    }

    normal_kernel<<<16, 256, 0, stream>>>(preds, normals, dS0, dF0,
                                          iF0, iF1, iF2, iF3, partials);
    final_kernel<<<1, 64, 0, stream>>>(partials, out);
}